// Round 14
// baseline (155.866 us; speedup 1.0000x reference)
//
#include <hip/hip_runtime.h>
#include <hip/hip_bf16.h>

// ---- problem constants ----
constexpr int NN = 16000, NE = 48000, NF = 32000;
constexpr int ND = 64, NB = 32, NG = 32;
constexpr int HIDN = 256, NCLS = 10;
constexpr int CHB = 32;                       // chunk-blocks per graph in k_ecc
constexpr int EFB = (NE + NF + 255) / 256;    // 313 scatter blocks (inside k_pre)
constexpr int PREB = (NN * ND) / 256;         // 4000 blocks in k_pre
constexpr int CAPE = 4096, CAPF = 4096;       // bucket capacity (mean 1500/1000)
constexpr float KLOG = 144.26950408889634f;   // 100 * log2(e)
constexpr float DLT  = 9.307710457348151f;    // (2/31) * KLOG
constexpr float INV_DLT = 0.10743849569269015f;
constexpr int HBINS = 35;                     // 32 real + 3 pad (max write jlo+3 <= 34)

// ---- ws word layout (~5 MB of the 268 MB ws) ----
constexpr int NH_OFF   = 0;                       // [NN*ND] f32 node heights
constexpr int ECCF_OFF = NH_OFF + NN * ND;        // [NG*NB*ND]=65536 f32 ecc
constexpr int CUR_OFF  = ECCF_OFF + NG * NB * ND; // [64] u32 append cursors  (memset)
constexpr int DONE_OFF = CUR_OFF + 64;            // [32] u32 mlp done ctrs   (memset)
constexpr int NOFS_OFF = DONE_OFF + 32;           // [33] i32 node boundaries
constexpr int PE_OFF   = NOFS_OFF + 34;           // u16[NG*CAPE]
constexpr int PF_OFF   = PE_OFF + NG * CAPE / 2;  // u16[NG*CAPF]
constexpr int HB_OFF   = PF_OFF + NG * CAPF / 2;  // [NG*HIDN] f32 hidden acts
constexpr int ZERO_CNT = NG * NB * ND;            // eccf zeroed in k_pre

__device__ __forceinline__ int clamp_node(int n) {
    return ((unsigned)n < (unsigned)NN) ? n : 0;
}
template<bool BF> __device__ __forceinline__ float ldf(const void* p, int i) {
    return BF ? __bfloat162float(((const __hip_bfloat16*)p)[i]) : ((const float*)p)[i];
}
template<bool I64> __device__ __forceinline__ int ldi(const int* p, int i) {
    return I64 ? p[2 * i] : p[i];
}

// per-block dtype self-detection (wave-uniform via ballot)
__device__ __forceinline__ bool detect_bf(const void* xp) {
    const unsigned* xw = (const unsigned*)xp;
    unsigned w = xw[threadIdx.x & 63];
    return __ballot(((w >> 23) & 0xFFu) >= 200u) != 0ull;
}
__device__ __forceinline__ bool detect_i64(const int* eip) {
    const unsigned* eiw = (const unsigned*)eip;
    unsigned o = eiw[2 * (threadIdx.x & 63) + 1];
    return __ballot(o != 0u) == 0ull;
}

// 4-tap delta-histogram sigmoid (validated R12/R13): 3 exact rcp taps +
// saturation step at T=14 (err <= 6.5e-5/element). Lane d owns column d of its
// wave's private copy: plain LDS RMW, no atomics.
__device__ __forceinline__ void accum_hist(float h, float s, float* hb) {
    const float KDEC = __builtin_amdgcn_exp2f(-DLT);
    float hkL = fmaf(h, KLOG, KLOG);              // t_j = hkL - j*DLT
    float fl = floorf((hkL - 14.0f) * INV_DLT);
    int jlo = (int)fl + 1;                        // first j with t_j < 14
    if (jlo >= 32) return;                        // everything ~0
    float t0 = fmaf(-(fl + 1.0f), DLT, hkL);      // t at jlo, in [4.69, 14)
    float e = __builtin_amdgcn_exp2f(t0);
    float prev = 0.0f;
#pragma unroll
    for (int m = 0; m < 3; m++) {
        float sig = __builtin_amdgcn_rcpf(1.0f + e);
        int idx = max(jlo + m, 0);
        hb[idx * 64] += s * (sig - prev);
        prev = sig; e *= KDEC;
    }
    int idx3 = max(jlo + 3, 0);
    hb[idx3 * 64] += s * (1.0f - prev);
}

// K0: fused prelude — heights, eccf zero, node boundaries, APPEND-SCATTER.
// No histogram/prefix: buckets are fixed-capacity, cursors zeroed by memset.
template<bool BF, bool I64>
__device__ __forceinline__ void pre_body(const void* x, const void* nw, const void* v,
                                         const int* ei, const int* fc, const int* batch,
                                         float* wsf, int* wsi, unsigned* cur,
                                         unsigned short* pe, unsigned short* pf,
                                         unsigned* cnt, unsigned* base) {
    int t = threadIdx.x;
    int gid = blockIdx.x * 256 + t;

    if (gid < ZERO_CNT) wsf[ECCF_OFF + gid] = 0.0f;

    if (gid < NN) {                                // node range boundaries
        int gn = ldi<I64>(batch, gid) & (NG - 1);
        int gp = (gid > 0) ? (ldi<I64>(batch, gid - 1) & (NG - 1)) : -1;
        for (int gg = gp + 1; gg <= gn; gg++) wsi[NOFS_OFF + gg] = gid;
        if (gid == NN - 1)
            for (int gg = gn + 1; gg <= NG; gg++) wsi[NOFS_OFF + gg] = NN;
    }

    {                                              // heights: gid in [0, NN*ND)
        int n = gid >> 6, d = gid & 63;
        float h = fmaf(ldf<BF>(x, n*3+2), ldf<BF>(v, 2*ND+d),
                  fmaf(ldf<BF>(x, n*3+1), ldf<BF>(v, ND+d),
                       ldf<BF>(x, n*3+0) * ldf<BF>(v, d))) * ldf<BF>(nw, n);
        wsf[NH_OFF + gid] = h;
    }

    if (blockIdx.x < EFB) {                        // append-scatter (block-uniform)
        if (t < 64) cnt[t] = 0;
        __syncthreads();
        int id = blockIdx.x * 256 + t;
        int bin = 0; unsigned rank = 0; bool act = false;
        if (id < NE + NF) {
            if (id < NE) bin = ldi<I64>(batch, clamp_node(ldi<I64>(ei, id))) & 31;
            else bin = 32 + (ldi<I64>(batch, clamp_node(ldi<I64>(fc, id - NE))) & 31);
            act = true;
            rank = atomicAdd(&cnt[bin], 1u);
        }
        __syncthreads();
        if (t < 64) base[t] = cnt[t] ? atomicAdd(&cur[t], cnt[t]) : 0u;
        __syncthreads();
        if (act) {
            int off = (int)(base[bin] + rank);
            if (bin < 32) { if (off < CAPE) pe[bin * CAPE + off] = (unsigned short)id; }
            else { if (off < CAPF) pf[(bin - 32) * CAPF + off] = (unsigned short)(id - NE); }
        }
    }
}
__global__ __launch_bounds__(256) void k_pre(const void* __restrict__ x,
                                             const void* __restrict__ nw,
                                             const void* __restrict__ v,
                                             const int* __restrict__ ei,
                                             const int* __restrict__ fc,
                                             const int* __restrict__ batch,
                                             float* __restrict__ wsf,
                                             int* __restrict__ wsi,
                                             unsigned* __restrict__ cur,
                                             unsigned short* __restrict__ pe,
                                             unsigned short* __restrict__ pf) {
    __shared__ unsigned cnt[64], base[64];
    bool bf = detect_bf(x), i64 = detect_i64(ei);
    if (bf)  { if (i64) pre_body<true,true >(x,nw,v,ei,fc,batch,wsf,wsi,cur,pe,pf,cnt,base);
               else     pre_body<true,false>(x,nw,v,ei,fc,batch,wsf,wsi,cur,pe,pf,cnt,base); }
    else     { if (i64) pre_body<false,true >(x,nw,v,ei,fc,batch,wsf,wsi,cur,pe,pf,cnt,base);
               else     pre_body<false,false>(x,nw,v,ei,fc,batch,wsf,wsi,cur,pe,pf,cnt,base); }
}

// K1: ecc via wave-private LDS delta-histograms (no atomics in hot loop).
// grid = NG*CHB = 1024 blocks = 4/CU; wave-stream per element, lane = dir.
template<bool BF, bool I64>
__device__ __forceinline__ void ecc_body(const int* ei, const int* fc,
                                         const void* ew, const void* fw,
                                         const float* nh, const int* wsi,
                                         const unsigned* cur, float* eccf,
                                         const unsigned short* pe,
                                         const unsigned short* pf,
                                         float* hist) {
    int t = threadIdx.x;
    int d = t & 63;
    int w = __builtin_amdgcn_readfirstlane(t) >> 6;
    int g  = blockIdx.x >> 5;                 // / CHB
    int cb = blockIdx.x & (CHB - 1);
    int sid = cb * 4 + w;
    const int S = CHB * 4;                    // 128 streams per graph

    for (int j = t; j < 4 * HBINS * 64; j += 256) hist[j] = 0.0f;
    __syncthreads();

    float* hb = hist + w * (HBINS * 64) + d;  // wave-private copy, lane-owned column

    // nodes (+1)
    int ns = wsi[NOFS_OFF + g], nend = wsi[NOFS_OFF + g + 1];
    for (int i = ns + sid; i < nend; i += S)
        accum_hist(nh[i * ND + d], 1.0f, hb);

    // edges (-1)
    int ecnt = min((int)cur[g], CAPE);
    for (int i = sid; i < ecnt; i += S) {
        int e = pe[g * CAPE + i];
        int a = clamp_node(ldi<I64>(ei, e)), b = clamp_node(ldi<I64>(ei, NE + e));
        float h = fmaxf(nh[a * ND + d], nh[b * ND + d]) * ldf<BF>(ew, e);
        accum_hist(h, -1.0f, hb);
    }

    // faces (+1)
    int fcnt = min((int)cur[32 + g], CAPF);
    for (int i = sid; i < fcnt; i += S) {
        int f = pf[g * CAPF + i];
        int a = clamp_node(ldi<I64>(fc, f)), b = clamp_node(ldi<I64>(fc, NF + f));
        int c = clamp_node(ldi<I64>(fc, 2*NF + f));
        float h = fmaxf(fmaxf(nh[a*ND+d], nh[b*ND+d]), nh[c*ND+d]) * ldf<BF>(fw, f);
        accum_hist(h, 1.0f, hb);
    }

    __syncthreads();
    // collapse 4 wave copies with full block, then prefix over j; one atomic/(j,d)
    for (int o = t; o < HBINS * 64; o += 256)
        hist[o] += hist[HBINS*64 + o] + hist[2*HBINS*64 + o] + hist[3*HBINS*64 + o];
    __syncthreads();
    if (t < 64) {
        float run = 0.0f;
        float* eb = eccf + g * (NB * ND) + t;
        for (int j = 0; j < 32; j++) {
            run += hist[j * 64 + t];
            atomicAdd(eb + j * 64, run);
        }
    }
}
__global__ __launch_bounds__(256, 4) void k_ecc(const int* __restrict__ ei,
                                                const int* __restrict__ fc,
                                                const void* __restrict__ ew,
                                                const void* __restrict__ fw,
                                                const float* __restrict__ nh,
                                                const int* __restrict__ wsi,
                                                const unsigned* __restrict__ cur,
                                                float* __restrict__ eccf,
                                                const unsigned short* __restrict__ pe,
                                                const unsigned short* __restrict__ pf,
                                                const void* __restrict__ x) {
    __shared__ float hist[4 * HBINS * 64];         // 35.8 KB, wave-private copies
    bool bf = detect_bf(x), i64 = detect_i64(ei);
    if (bf)  { if (i64) ecc_body<true,true >(ei,fc,ew,fw,nh,wsi,cur,eccf,pe,pf,hist);
               else     ecc_body<true,false>(ei,fc,ew,fw,nh,wsi,cur,eccf,pe,pf,hist); }
    else     { if (i64) ecc_body<false,true >(ei,fc,ew,fw,nh,wsi,cur,eccf,pe,pf,hist);
               else     ecc_body<false,false>(ei,fc,ew,fw,nh,wsi,cur,eccf,pe,pf,hist); }
}

// K2: fused MLP. 256 blocks do layer-1 chunks; the LAST block per graph
// (done-counter) runs layer 2 inline. hbuf crosses blocks within the kernel,
// so it uses agent-scope atomic stores/loads (per-XCD L2s are not coherent;
// the 0xAA ws-poison can sit dirty in another XCD's L2 — G16).
template<bool BF>
__device__ __forceinline__ void mlp_body(const void* W1, const void* b1,
                                         const void* W2, const void* b2,
                                         const float* eccf, float* hbuf,
                                         unsigned* done, void* outv,
                                         float* red, float* pr, int* lastflag) {
    int g = blockIdx.x >> 3, hc = blockIdx.x & 7;
    int t = threadIdx.x;

    const float4* fp = (const float4*)(eccf + g * (NB * ND) + t * 8);
    float4 fa = fp[0], fb = fp[1];
    float fl[8] = {fa.x, fa.y, fa.z, fa.w, fb.x, fb.y, fb.z, fb.w};

    if (hc == 0) {                              // flush flat output (once per graph)
        int ob = NG * NCLS + g * (NB * ND) + t * 8;
        if (BF) {
#pragma unroll
            for (int j = 0; j < 8; j++)
                ((__hip_bfloat16*)outv)[ob + j] = __float2bfloat16(fl[j]);
        } else {
            ((float4*)((float*)outv + ob))[0] = fa;
            ((float4*)((float*)outv + ob))[1] = fb;
        }
    }

    float acc[32];
#pragma unroll
    for (int r = 0; r < 32; r++) acc[r] = 0.0f;
#pragma unroll 4
    for (int r = 0; r < 32; r++) {
        size_t wb = (size_t)(hc * 32 + r) * (NB * ND) + t * 8;
        float wv[8];
        if (BF) {
            uint4 u = *(const uint4*)((const __hip_bfloat16*)W1 + wb);
            wv[0] = __uint_as_float(u.x << 16); wv[1] = __uint_as_float(u.x & 0xffff0000u);
            wv[2] = __uint_as_float(u.y << 16); wv[3] = __uint_as_float(u.y & 0xffff0000u);
            wv[4] = __uint_as_float(u.z << 16); wv[5] = __uint_as_float(u.z & 0xffff0000u);
            wv[6] = __uint_as_float(u.w << 16); wv[7] = __uint_as_float(u.w & 0xffff0000u);
        } else {
            float4 a = *(const float4*)((const float*)W1 + wb);
            float4 b = *(const float4*)((const float*)W1 + wb + 4);
            wv[0]=a.x; wv[1]=a.y; wv[2]=a.z; wv[3]=a.w;
            wv[4]=b.x; wv[5]=b.y; wv[6]=b.z; wv[7]=b.w;
        }
        float s = 0.0f;
#pragma unroll
        for (int j = 0; j < 8; j++) s = fmaf(wv[j], fl[j], s);
        acc[r] = s;
    }

#pragma unroll
    for (int r = 0; r < 32; r++) red[t * 33 + r] = acc[r];
    __syncthreads();
    {
        int r = t >> 3, s8 = t & 7;
        float sum = 0.0f;
#pragma unroll
        for (int i = 0; i < 32; i++) sum += red[(s8 * 32 + i) * 33 + r];
        pr[r * 8 + s8] = sum;
    }
    __syncthreads();
    if (t < 32) {
        float h = ldf<BF>(b1, hc * 32 + t);
#pragma unroll
        for (int s8 = 0; s8 < 8; s8++) h += pr[t * 8 + s8];
        __hip_atomic_store(&hbuf[g * HIDN + hc * 32 + t], fmaxf(h, 0.0f),
                           __ATOMIC_RELAXED, __HIP_MEMORY_SCOPE_AGENT);
    }
    __threadfence();
    if (t == 0) *lastflag = ((int)atomicAdd(&done[g], 1u) == 7);
    __syncthreads();
    if (!*lastflag) return;

    // ---- layer 2 (last block of this graph) ----
    __threadfence();
    float* hs = red;                           // reuse scratch
    hs[t] = __hip_atomic_load(&hbuf[g * HIDN + t],
                              __ATOMIC_RELAXED, __HIP_MEMORY_SCOPE_AGENT);
    __syncthreads();
    int w = t >> 6, lane = t & 63;
    for (int c = w; c < NCLS; c += 4) {
        float p = hs[lane]        * ldf<BF>(W2, c * HIDN + lane)
                + hs[lane + 64]   * ldf<BF>(W2, c * HIDN + lane + 64)
                + hs[lane + 128]  * ldf<BF>(W2, c * HIDN + lane + 128)
                + hs[lane + 192]  * ldf<BF>(W2, c * HIDN + lane + 192);
#pragma unroll
        for (int off = 32; off >= 1; off >>= 1) p += __shfl_xor(p, off);
        if (lane == 0) {
            float r = p + ldf<BF>(b2, c);
            if (BF) ((__hip_bfloat16*)outv)[g * NCLS + c] = __float2bfloat16(r);
            else    ((float*)outv)[g * NCLS + c] = r;
        }
    }
}
__global__ __launch_bounds__(256) void k_mlp(const void* __restrict__ W1,
                                             const void* __restrict__ b1,
                                             const void* __restrict__ W2,
                                             const void* __restrict__ b2,
                                             const float* __restrict__ eccf,
                                             float* __restrict__ hbuf,
                                             unsigned* __restrict__ done,
                                             void* __restrict__ outv,
                                             const void* __restrict__ x) {
    __shared__ float red[256 * 33];
    __shared__ float pr[256];
    __shared__ int lastflag;
    if (detect_bf(x)) mlp_body<true>(W1, b1, W2, b2, eccf, hbuf, done, outv, red, pr, &lastflag);
    else              mlp_body<false>(W1, b1, W2, b2, eccf, hbuf, done, outv, red, pr, &lastflag);
}

extern "C" void kernel_launch(void* const* d_in, const int* in_sizes, int n_in,
                              void* d_out, int out_size, void* d_ws, size_t ws_size,
                              hipStream_t stream) {
    const void* x  = d_in[0];
    const void* nw = d_in[1];
    const void* ew = d_in[2];
    const void* fw = d_in[3];
    const void* v  = d_in[4];
    const void* W1 = d_in[5];
    const void* b1 = d_in[6];
    const void* W2 = d_in[7];
    const void* b2 = d_in[8];
    const int* ei    = (const int*)d_in[9];
    const int* fc    = (const int*)d_in[10];
    const int* batch = (const int*)d_in[11];

    float*    wsf = (float*)d_ws;
    unsigned* wsu = (unsigned*)d_ws;
    int*      wsi = (int*)d_ws;
    float*    nh   = wsf + NH_OFF;
    float*    eccf = wsf + ECCF_OFF;
    unsigned* cur  = wsu + CUR_OFF;
    unsigned* done = wsu + DONE_OFF;
    float*    hbuf = wsf + HB_OFF;
    unsigned short* pe = (unsigned short*)(wsi + PE_OFF);
    unsigned short* pf = (unsigned short*)(wsi + PF_OFF);

    // zero cursors + done counters (384 B)
    hipMemsetAsync((char*)d_ws + (size_t)CUR_OFF * 4, 0, 96 * 4, stream);

    k_pre<<<PREB, 256, 0, stream>>>(x, nw, v, ei, fc, batch, wsf, wsi, cur, pe, pf);
    k_ecc<<<NG * CHB, 256, 0, stream>>>(ei, fc, ew, fw, nh, wsi, cur, eccf, pe, pf, x);
    k_mlp<<<NG * 8, 256, 0, stream>>>(W1, b1, W2, b2, eccf, hbuf, done, d_out, x);
}

// Round 15
// 133.278 us; speedup vs baseline: 1.1695x; 1.1695x over previous
//
#include <hip/hip_runtime.h>
#include <hip/hip_bf16.h>

// ---- problem constants ----
constexpr int NN = 16000, NE = 48000, NF = 32000;
constexpr int ND = 64, NB = 32, NG = 32;
constexpr int HIDN = 256, NCLS = 10;
constexpr int CHB = 32;                       // chunk-blocks per graph in k_ecc
constexpr int EFB = (NE + NF + 255) / 256;    // 313 scatter blocks (inside k_pre)
constexpr int PREB = (NN * ND) / 256;         // 4000 blocks in k_pre
constexpr int CAPE = 4096, CAPF = 4096;       // bucket capacity (mean 1500/1000)
constexpr float KLOG = 144.26950408889634f;   // 100 * log2(e)
constexpr float DLT  = 9.307710457348151f;    // (2/31) * KLOG
constexpr float INV_DLT = 0.10743849569269015f;
constexpr int HBINS = 35;                     // 32 real + 3 pad (max write jlo+3 <= 34)

// ---- ws word layout (~5 MB of the 268 MB ws) ----
constexpr int NH_OFF   = 0;                       // [NN*ND] f32 node heights
constexpr int ECCF_OFF = NH_OFF + NN * ND;        // [NG*NB*ND]=65536 f32 ecc
constexpr int CUR_OFF  = ECCF_OFF + NG * NB * ND; // [64] u32 append cursors (memset)
constexpr int NOFS_OFF = CUR_OFF + 64;            // [33] i32 node boundaries
constexpr int PE_OFF   = NOFS_OFF + 34;           // u16[NG*CAPE]
constexpr int PF_OFF   = PE_OFF + NG * CAPE / 2;  // u16[NG*CAPF]
constexpr int HB_OFF   = PF_OFF + NG * CAPF / 2;  // [NG*HIDN] f32 hidden acts
constexpr int ZERO_CNT = NG * NB * ND;            // eccf zeroed in k_pre

__device__ __forceinline__ int clamp_node(int n) {
    return ((unsigned)n < (unsigned)NN) ? n : 0;
}
template<bool BF> __device__ __forceinline__ float ldf(const void* p, int i) {
    return BF ? __bfloat162float(((const __hip_bfloat16*)p)[i]) : ((const float*)p)[i];
}
template<bool I64> __device__ __forceinline__ int ldi(const int* p, int i) {
    return I64 ? p[2 * i] : p[i];
}

// per-block dtype self-detection (wave-uniform via ballot)
__device__ __forceinline__ bool detect_bf(const void* xp) {
    const unsigned* xw = (const unsigned*)xp;
    unsigned w = xw[threadIdx.x & 63];
    return __ballot(((w >> 23) & 0xFFu) >= 200u) != 0ull;
}
__device__ __forceinline__ bool detect_i64(const int* eip) {
    const unsigned* eiw = (const unsigned*)eip;
    unsigned o = eiw[2 * (threadIdx.x & 63) + 1];
    return __ballot(o != 0u) == 0ull;
}

// 4-tap delta-histogram sigmoid (validated R12-R14): 3 exact rcp taps +
// saturation step at T=14 (err <= 6.5e-5/element). Lane d owns column d of its
// wave's private copy: plain LDS RMW, no atomics.
__device__ __forceinline__ void accum_hist(float h, float s, float* hb) {
    const float KDEC = __builtin_amdgcn_exp2f(-DLT);
    float hkL = fmaf(h, KLOG, KLOG);              // t_j = hkL - j*DLT
    float fl = floorf((hkL - 14.0f) * INV_DLT);
    int jlo = (int)fl + 1;                        // first j with t_j < 14
    if (jlo >= 32) return;                        // everything ~0
    float t0 = fmaf(-(fl + 1.0f), DLT, hkL);      // t at jlo, in [4.69, 14)
    float e = __builtin_amdgcn_exp2f(t0);
    float prev = 0.0f;
#pragma unroll
    for (int m = 0; m < 3; m++) {
        float sig = __builtin_amdgcn_rcpf(1.0f + e);
        int idx = max(jlo + m, 0);
        hb[idx * 64] += s * (sig - prev);
        prev = sig; e *= KDEC;
    }
    int idx3 = max(jlo + 3, 0);
    hb[idx3 * 64] += s * (1.0f - prev);
}

// K0: fused prelude — heights, eccf zero, node boundaries, append-scatter.
template<bool BF, bool I64>
__device__ __forceinline__ void pre_body(const void* x, const void* nw, const void* v,
                                         const int* ei, const int* fc, const int* batch,
                                         float* wsf, int* wsi, unsigned* cur,
                                         unsigned short* pe, unsigned short* pf,
                                         unsigned* cnt, unsigned* base) {
    int t = threadIdx.x;
    int gid = blockIdx.x * 256 + t;

    if (gid < ZERO_CNT) wsf[ECCF_OFF + gid] = 0.0f;

    if (gid < NN) {                                // node range boundaries
        int gn = ldi<I64>(batch, gid) & (NG - 1);
        int gp = (gid > 0) ? (ldi<I64>(batch, gid - 1) & (NG - 1)) : -1;
        for (int gg = gp + 1; gg <= gn; gg++) wsi[NOFS_OFF + gg] = gid;
        if (gid == NN - 1)
            for (int gg = gn + 1; gg <= NG; gg++) wsi[NOFS_OFF + gg] = NN;
    }

    {                                              // heights: gid in [0, NN*ND)
        int n = gid >> 6, d = gid & 63;
        float h = fmaf(ldf<BF>(x, n*3+2), ldf<BF>(v, 2*ND+d),
                  fmaf(ldf<BF>(x, n*3+1), ldf<BF>(v, ND+d),
                       ldf<BF>(x, n*3+0) * ldf<BF>(v, d))) * ldf<BF>(nw, n);
        wsf[NH_OFF + gid] = h;
    }

    if (blockIdx.x < EFB) {                        // append-scatter (block-uniform)
        if (t < 64) cnt[t] = 0;
        __syncthreads();
        int id = blockIdx.x * 256 + t;
        int bin = 0; unsigned rank = 0; bool act = false;
        if (id < NE + NF) {
            if (id < NE) bin = ldi<I64>(batch, clamp_node(ldi<I64>(ei, id))) & 31;
            else bin = 32 + (ldi<I64>(batch, clamp_node(ldi<I64>(fc, id - NE))) & 31);
            act = true;
            rank = atomicAdd(&cnt[bin], 1u);
        }
        __syncthreads();
        if (t < 64) base[t] = cnt[t] ? atomicAdd(&cur[t], cnt[t]) : 0u;
        __syncthreads();
        if (act) {
            int off = (int)(base[bin] + rank);
            if (bin < 32) { if (off < CAPE) pe[bin * CAPE + off] = (unsigned short)id; }
            else { if (off < CAPF) pf[(bin - 32) * CAPF + off] = (unsigned short)(id - NE); }
        }
    }
}
__global__ __launch_bounds__(256) void k_pre(const void* __restrict__ x,
                                             const void* __restrict__ nw,
                                             const void* __restrict__ v,
                                             const int* __restrict__ ei,
                                             const int* __restrict__ fc,
                                             const int* __restrict__ batch,
                                             float* __restrict__ wsf,
                                             int* __restrict__ wsi,
                                             unsigned* __restrict__ cur,
                                             unsigned short* __restrict__ pe,
                                             unsigned short* __restrict__ pf) {
    __shared__ unsigned cnt[64], base[64];
    bool bf = detect_bf(x), i64 = detect_i64(ei);
    if (bf)  { if (i64) pre_body<true,true >(x,nw,v,ei,fc,batch,wsf,wsi,cur,pe,pf,cnt,base);
               else     pre_body<true,false>(x,nw,v,ei,fc,batch,wsf,wsi,cur,pe,pf,cnt,base); }
    else     { if (i64) pre_body<false,true >(x,nw,v,ei,fc,batch,wsf,wsi,cur,pe,pf,cnt,base);
               else     pre_body<false,false>(x,nw,v,ei,fc,batch,wsf,wsi,cur,pe,pf,cnt,base); }
}

// K1: ecc via wave-private LDS delta-histograms (no atomics in hot loop).
template<bool BF, bool I64>
__device__ __forceinline__ void ecc_body(const int* ei, const int* fc,
                                         const void* ew, const void* fw,
                                         const float* nh, const int* wsi,
                                         const unsigned* cur, float* eccf,
                                         const unsigned short* pe,
                                         const unsigned short* pf,
                                         float* hist) {
    int t = threadIdx.x;
    int d = t & 63;
    int w = __builtin_amdgcn_readfirstlane(t) >> 6;
    int g  = blockIdx.x >> 5;                 // / CHB
    int cb = blockIdx.x & (CHB - 1);
    int sid = cb * 4 + w;
    const int S = CHB * 4;                    // 128 streams per graph

    for (int j = t; j < 4 * HBINS * 64; j += 256) hist[j] = 0.0f;
    __syncthreads();

    float* hb = hist + w * (HBINS * 64) + d;  // wave-private copy, lane-owned column

    // nodes (+1)
    int ns = wsi[NOFS_OFF + g], nend = wsi[NOFS_OFF + g + 1];
    for (int i = ns + sid; i < nend; i += S)
        accum_hist(nh[i * ND + d], 1.0f, hb);

    // edges (-1)
    int ecnt = min((int)cur[g], CAPE);
    for (int i = sid; i < ecnt; i += S) {
        int e = pe[g * CAPE + i];
        int a = clamp_node(ldi<I64>(ei, e)), b = clamp_node(ldi<I64>(ei, NE + e));
        float h = fmaxf(nh[a * ND + d], nh[b * ND + d]) * ldf<BF>(ew, e);
        accum_hist(h, -1.0f, hb);
    }

    // faces (+1)
    int fcnt = min((int)cur[32 + g], CAPF);
    for (int i = sid; i < fcnt; i += S) {
        int f = pf[g * CAPF + i];
        int a = clamp_node(ldi<I64>(fc, f)), b = clamp_node(ldi<I64>(fc, NF + f));
        int c = clamp_node(ldi<I64>(fc, 2*NF + f));
        float h = fmaxf(fmaxf(nh[a*ND+d], nh[b*ND+d]), nh[c*ND+d]) * ldf<BF>(fw, f);
        accum_hist(h, 1.0f, hb);
    }

    __syncthreads();
    // collapse 4 wave copies with full block, then prefix over j; one atomic/(j,d)
    for (int o = t; o < HBINS * 64; o += 256)
        hist[o] += hist[HBINS*64 + o] + hist[2*HBINS*64 + o] + hist[3*HBINS*64 + o];
    __syncthreads();
    if (t < 64) {
        float run = 0.0f;
        float* eb = eccf + g * (NB * ND) + t;
        for (int j = 0; j < 32; j++) {
            run += hist[j * 64 + t];
            atomicAdd(eb + j * 64, run);
        }
    }
}
__global__ __launch_bounds__(256, 4) void k_ecc(const int* __restrict__ ei,
                                                const int* __restrict__ fc,
                                                const void* __restrict__ ew,
                                                const void* __restrict__ fw,
                                                const float* __restrict__ nh,
                                                const int* __restrict__ wsi,
                                                const unsigned* __restrict__ cur,
                                                float* __restrict__ eccf,
                                                const unsigned short* __restrict__ pe,
                                                const unsigned short* __restrict__ pf,
                                                const void* __restrict__ x) {
    __shared__ float hist[4 * HBINS * 64];         // 35.8 KB, wave-private copies
    bool bf = detect_bf(x), i64 = detect_i64(ei);
    if (bf)  { if (i64) ecc_body<true,true >(ei,fc,ew,fw,nh,wsi,cur,eccf,pe,pf,hist);
               else     ecc_body<true,false>(ei,fc,ew,fw,nh,wsi,cur,eccf,pe,pf,hist); }
    else     { if (i64) ecc_body<false,true >(ei,fc,ew,fw,nh,wsi,cur,eccf,pe,pf,hist);
               else     ecc_body<false,false>(ei,fc,ew,fw,nh,wsi,cur,eccf,pe,pf,hist); }
}

// K2: MLP layer 1 + fused flat-output flush. grid = 32 graphs x 8 hid-chunks.
// Plain stores to hbuf; the kernel boundary before k_mlp2 provides sync.
template<bool BF>
__device__ __forceinline__ void mlp1_body(const void* W1, const void* b1,
                                          const float* eccf, float* hbuf,
                                          void* outv, float* red, float* pr) {
    int g = blockIdx.x >> 3, hc = blockIdx.x & 7;
    int t = threadIdx.x;

    const float4* fp = (const float4*)(eccf + g * (NB * ND) + t * 8);
    float4 fa = fp[0], fb = fp[1];
    float fl[8] = {fa.x, fa.y, fa.z, fa.w, fb.x, fb.y, fb.z, fb.w};

    if (hc == 0) {                              // flush flat output (once per graph)
        int ob = NG * NCLS + g * (NB * ND) + t * 8;
        if (BF) {
#pragma unroll
            for (int j = 0; j < 8; j++)
                ((__hip_bfloat16*)outv)[ob + j] = __float2bfloat16(fl[j]);
        } else {
            ((float4*)((float*)outv + ob))[0] = fa;
            ((float4*)((float*)outv + ob))[1] = fb;
        }
    }

    float acc[32];
#pragma unroll
    for (int r = 0; r < 32; r++) acc[r] = 0.0f;
#pragma unroll 4
    for (int r = 0; r < 32; r++) {
        size_t wb = (size_t)(hc * 32 + r) * (NB * ND) + t * 8;
        float wv[8];
        if (BF) {
            uint4 u = *(const uint4*)((const __hip_bfloat16*)W1 + wb);
            wv[0] = __uint_as_float(u.x << 16); wv[1] = __uint_as_float(u.x & 0xffff0000u);
            wv[2] = __uint_as_float(u.y << 16); wv[3] = __uint_as_float(u.y & 0xffff0000u);
            wv[4] = __uint_as_float(u.z << 16); wv[5] = __uint_as_float(u.z & 0xffff0000u);
            wv[6] = __uint_as_float(u.w << 16); wv[7] = __uint_as_float(u.w & 0xffff0000u);
        } else {
            float4 a = *(const float4*)((const float*)W1 + wb);
            float4 b = *(const float4*)((const float*)W1 + wb + 4);
            wv[0]=a.x; wv[1]=a.y; wv[2]=a.z; wv[3]=a.w;
            wv[4]=b.x; wv[5]=b.y; wv[6]=b.z; wv[7]=b.w;
        }
        float s = 0.0f;
#pragma unroll
        for (int j = 0; j < 8; j++) s = fmaf(wv[j], fl[j], s);
        acc[r] = s;
    }

#pragma unroll
    for (int r = 0; r < 32; r++) red[t * 33 + r] = acc[r];
    __syncthreads();
    {
        int r = t >> 3, s8 = t & 7;
        float sum = 0.0f;
#pragma unroll
        for (int i = 0; i < 32; i++) sum += red[(s8 * 32 + i) * 33 + r];
        pr[r * 8 + s8] = sum;
    }
    __syncthreads();
    if (t < 32) {
        float h = ldf<BF>(b1, hc * 32 + t);
#pragma unroll
        for (int s8 = 0; s8 < 8; s8++) h += pr[t * 8 + s8];
        hbuf[g * HIDN + hc * 32 + t] = fmaxf(h, 0.0f);
    }
}
__global__ __launch_bounds__(256) void k_mlp1(const void* __restrict__ W1,
                                              const void* __restrict__ b1,
                                              const float* __restrict__ eccf,
                                              float* __restrict__ hbuf,
                                              void* __restrict__ outv,
                                              const void* __restrict__ x) {
    __shared__ float red[256 * 33];
    __shared__ float pr[256];
    if (detect_bf(x)) mlp1_body<true>(W1, b1, eccf, hbuf, outv, red, pr);
    else              mlp1_body<false>(W1, b1, eccf, hbuf, outv, red, pr);
}

// K3: MLP layer 2. one block per graph; wave per class, shuffle reduce.
template<bool BF>
__device__ __forceinline__ void mlp2_body(const void* W2, const void* b2,
                                          const float* hbuf, void* outv, float* hs) {
    int g = blockIdx.x, t = threadIdx.x;
    hs[t] = hbuf[g * HIDN + t];
    __syncthreads();
    int w = t >> 6, lane = t & 63;
    for (int c = w; c < NCLS; c += 4) {
        float p = hs[lane]        * ldf<BF>(W2, c * HIDN + lane)
                + hs[lane + 64]   * ldf<BF>(W2, c * HIDN + lane + 64)
                + hs[lane + 128]  * ldf<BF>(W2, c * HIDN + lane + 128)
                + hs[lane + 192]  * ldf<BF>(W2, c * HIDN + lane + 192);
#pragma unroll
        for (int off = 32; off >= 1; off >>= 1) p += __shfl_xor(p, off);
        if (lane == 0) {
            float r = p + ldf<BF>(b2, c);
            if (BF) ((__hip_bfloat16*)outv)[g * NCLS + c] = __float2bfloat16(r);
            else    ((float*)outv)[g * NCLS + c] = r;
        }
    }
}
__global__ __launch_bounds__(256) void k_mlp2(const void* __restrict__ W2,
                                              const void* __restrict__ b2,
                                              const float* __restrict__ hbuf,
                                              void* __restrict__ outv,
                                              const void* __restrict__ x) {
    __shared__ float hs[HIDN];
    if (detect_bf(x)) mlp2_body<true>(W2, b2, hbuf, outv, hs);
    else              mlp2_body<false>(W2, b2, hbuf, outv, hs);
}

extern "C" void kernel_launch(void* const* d_in, const int* in_sizes, int n_in,
                              void* d_out, int out_size, void* d_ws, size_t ws_size,
                              hipStream_t stream) {
    const void* x  = d_in[0];
    const void* nw = d_in[1];
    const void* ew = d_in[2];
    const void* fw = d_in[3];
    const void* v  = d_in[4];
    const void* W1 = d_in[5];
    const void* b1 = d_in[6];
    const void* W2 = d_in[7];
    const void* b2 = d_in[8];
    const int* ei    = (const int*)d_in[9];
    const int* fc    = (const int*)d_in[10];
    const int* batch = (const int*)d_in[11];

    float*    wsf = (float*)d_ws;
    unsigned* wsu = (unsigned*)d_ws;
    int*      wsi = (int*)d_ws;
    float*    nh   = wsf + NH_OFF;
    float*    eccf = wsf + ECCF_OFF;
    unsigned* cur  = wsu + CUR_OFF;
    float*    hbuf = wsf + HB_OFF;
    unsigned short* pe = (unsigned short*)(wsi + PE_OFF);
    unsigned short* pf = (unsigned short*)(wsi + PF_OFF);

    // zero append cursors (256 B)
    hipMemsetAsync((char*)d_ws + (size_t)CUR_OFF * 4, 0, 64 * 4, stream);

    k_pre<<<PREB, 256, 0, stream>>>(x, nw, v, ei, fc, batch, wsf, wsi, cur, pe, pf);
    k_ecc<<<NG * CHB, 256, 0, stream>>>(ei, fc, ew, fw, nh, wsi, cur, eccf, pe, pf, x);
    k_mlp1<<<NG * 8, 256, 0, stream>>>(W1, b1, eccf, hbuf, d_out, x);
    k_mlp2<<<NG, 256, 0, stream>>>(W2, b2, hbuf, d_out, x);
}

// Round 16
// 128.059 us; speedup vs baseline: 1.2171x; 1.0408x over previous
//
#include <hip/hip_runtime.h>
#include <hip/hip_bf16.h>

// ---- problem constants ----
constexpr int NN = 16000, NE = 48000, NF = 32000;
constexpr int ND = 64, NB = 32, NG = 32;
constexpr int HIDN = 256, NCLS = 10;
constexpr int CHB = 32;                       // chunk-blocks per graph in k_ecc
constexpr int EFB = (NE + NF + 255) / 256;    // 313 scatter blocks (inside k_pre)
constexpr int PREB = (NN * ND) / 256;         // 4000 blocks in k_pre
constexpr int CAPE = 4096, CAPF = 4096;       // bucket capacity (mean 1500/1000)
constexpr float KLOG = 144.26950408889634f;   // 100 * log2(e)
constexpr float DLT  = 9.307710457348151f;    // (2/31) * KLOG
constexpr float INV_DLT = 0.10743849569269015f;
constexpr int HBINS = 35;                     // 32 real + 3 pad (max write jlo+3 <= 34)

// ---- ws word layout (~5 MB of the 268 MB ws) ----
constexpr int NH_OFF   = 0;                       // [NN*ND] f32 node heights
constexpr int ECCF_OFF = NH_OFF + NN * ND;        // [NG*NB*ND]=65536 f32 ecc
constexpr int CUR_OFF  = ECCF_OFF + NG * NB * ND; // [64] u32 append cursors (memset)
constexpr int NOFS_OFF = CUR_OFF + 64;            // [33] i32 node boundaries
constexpr int PE_OFF   = NOFS_OFF + 34;           // u16[NG*CAPE]
constexpr int PF_OFF   = PE_OFF + NG * CAPE / 2;  // u16[NG*CAPF]
constexpr int HB_OFF   = PF_OFF + NG * CAPF / 2;  // [NG*HIDN] f32 hidden acts
constexpr int ZERO_CNT = NG * NB * ND;            // eccf zeroed in k_pre

__device__ __forceinline__ int clamp_node(int n) {
    return ((unsigned)n < (unsigned)NN) ? n : 0;
}
template<bool BF> __device__ __forceinline__ float ldf(const void* p, int i) {
    return BF ? __bfloat162float(((const __hip_bfloat16*)p)[i]) : ((const float*)p)[i];
}
template<bool I64> __device__ __forceinline__ int ldi(const int* p, int i) {
    return I64 ? p[2 * i] : p[i];
}

// per-block dtype self-detection (wave-uniform via ballot)
__device__ __forceinline__ bool detect_bf(const void* xp) {
    const unsigned* xw = (const unsigned*)xp;
    unsigned w = xw[threadIdx.x & 63];
    return __ballot(((w >> 23) & 0xFFu) >= 200u) != 0ull;
}
__device__ __forceinline__ bool detect_i64(const int* eip) {
    const unsigned* eiw = (const unsigned*)eip;
    unsigned o = eiw[2 * (threadIdx.x & 63) + 1];
    return __ballot(o != 0u) == 0ull;
}

// 4-tap delta-histogram sigmoid (validated R12-R15): 3 exact rcp taps +
// saturation step at T=14 (err <= 6.5e-5/element). Lane d owns column d of its
// wave's private copy: plain LDS RMW, no atomics; [bin][d] layout keeps
// banks = d mod 32 (2-way, free) regardless of data.
__device__ __forceinline__ void accum_hist(float h, float s, float* hb) {
    const float KDEC = __builtin_amdgcn_exp2f(-DLT);
    float hkL = fmaf(h, KLOG, KLOG);              // t_j = hkL - j*DLT
    float fl = floorf((hkL - 14.0f) * INV_DLT);
    int jlo = (int)fl + 1;                        // first j with t_j < 14
    if (jlo >= 32) return;                        // everything ~0
    float t0 = fmaf(-(fl + 1.0f), DLT, hkL);      // t at jlo, in [4.69, 14)
    float e = __builtin_amdgcn_exp2f(t0);
    float prev = 0.0f;
#pragma unroll
    for (int m = 0; m < 3; m++) {
        float sig = __builtin_amdgcn_rcpf(1.0f + e);
        int idx = max(jlo + m, 0);
        hb[idx * 64] += s * (sig - prev);
        prev = sig; e *= KDEC;
    }
    int idx3 = max(jlo + 3, 0);
    hb[idx3 * 64] += s * (1.0f - prev);
}

// K0: fused prelude — heights, eccf zero, node boundaries, append-scatter.
template<bool BF, bool I64>
__device__ __forceinline__ void pre_body(const void* x, const void* nw, const void* v,
                                         const int* ei, const int* fc, const int* batch,
                                         float* wsf, int* wsi, unsigned* cur,
                                         unsigned short* pe, unsigned short* pf,
                                         unsigned* cnt, unsigned* base) {
    int t = threadIdx.x;
    int gid = blockIdx.x * 256 + t;

    if (gid < ZERO_CNT) wsf[ECCF_OFF + gid] = 0.0f;

    if (gid < NN) {                                // node range boundaries
        int gn = ldi<I64>(batch, gid) & (NG - 1);
        int gp = (gid > 0) ? (ldi<I64>(batch, gid - 1) & (NG - 1)) : -1;
        for (int gg = gp + 1; gg <= gn; gg++) wsi[NOFS_OFF + gg] = gid;
        if (gid == NN - 1)
            for (int gg = gn + 1; gg <= NG; gg++) wsi[NOFS_OFF + gg] = NN;
    }

    {                                              // heights: gid in [0, NN*ND)
        int n = gid >> 6, d = gid & 63;
        float h = fmaf(ldf<BF>(x, n*3+2), ldf<BF>(v, 2*ND+d),
                  fmaf(ldf<BF>(x, n*3+1), ldf<BF>(v, ND+d),
                       ldf<BF>(x, n*3+0) * ldf<BF>(v, d))) * ldf<BF>(nw, n);
        wsf[NH_OFF + gid] = h;
    }

    if (blockIdx.x < EFB) {                        // append-scatter (block-uniform)
        if (t < 64) cnt[t] = 0;
        __syncthreads();
        int id = blockIdx.x * 256 + t;
        int bin = 0; unsigned rank = 0; bool act = false;
        if (id < NE + NF) {
            if (id < NE) bin = ldi<I64>(batch, clamp_node(ldi<I64>(ei, id))) & 31;
            else bin = 32 + (ldi<I64>(batch, clamp_node(ldi<I64>(fc, id - NE))) & 31);
            act = true;
            rank = atomicAdd(&cnt[bin], 1u);
        }
        __syncthreads();
        if (t < 64) base[t] = cnt[t] ? atomicAdd(&cur[t], cnt[t]) : 0u;
        __syncthreads();
        if (act) {
            int off = (int)(base[bin] + rank);
            if (bin < 32) { if (off < CAPE) pe[bin * CAPE + off] = (unsigned short)id; }
            else { if (off < CAPF) pf[(bin - 32) * CAPF + off] = (unsigned short)(id - NE); }
        }
    }
}
__global__ __launch_bounds__(256) void k_pre(const void* __restrict__ x,
                                             const void* __restrict__ nw,
                                             const void* __restrict__ v,
                                             const int* __restrict__ ei,
                                             const int* __restrict__ fc,
                                             const int* __restrict__ batch,
                                             float* __restrict__ wsf,
                                             int* __restrict__ wsi,
                                             unsigned* __restrict__ cur,
                                             unsigned short* __restrict__ pe,
                                             unsigned short* __restrict__ pf) {
    __shared__ unsigned cnt[64], base[64];
    bool bf = detect_bf(x), i64 = detect_i64(ei);
    if (bf)  { if (i64) pre_body<true,true >(x,nw,v,ei,fc,batch,wsf,wsi,cur,pe,pf,cnt,base);
               else     pre_body<true,false>(x,nw,v,ei,fc,batch,wsf,wsi,cur,pe,pf,cnt,base); }
    else     { if (i64) pre_body<false,true >(x,nw,v,ei,fc,batch,wsf,wsi,cur,pe,pf,cnt,base);
               else     pre_body<false,false>(x,nw,v,ei,fc,batch,wsf,wsi,cur,pe,pf,cnt,base); }
}

// K1: ecc via wave-private LDS delta-histograms; 2-element unrolled streams
// (loads for both elements issue before either sigmoid/DS chain -> latency
// overlap, the R6 lesson applied to this loop shape).
template<bool BF, bool I64>
__device__ __forceinline__ void ecc_body(const int* ei, const int* fc,
                                         const void* ew, const void* fw,
                                         const float* nh, const int* wsi,
                                         const unsigned* cur, float* eccf,
                                         const unsigned short* pe,
                                         const unsigned short* pf,
                                         float* hist) {
    int t = threadIdx.x;
    int d = t & 63;
    int w = __builtin_amdgcn_readfirstlane(t) >> 6;
    int g  = blockIdx.x >> 5;                 // / CHB
    int cb = blockIdx.x & (CHB - 1);
    int sid = cb * 4 + w;
    const int S = CHB * 4;                    // 128 streams per graph

    for (int j = t; j < 4 * HBINS * 64; j += 256) hist[j] = 0.0f;
    __syncthreads();

    float* hb = hist + w * (HBINS * 64) + d;  // wave-private copy, lane-owned column

    // nodes (+1), unroll 2
    int ns = wsi[NOFS_OFF + g], nend = wsi[NOFS_OFF + g + 1];
    int i = ns + sid;
    for (; i + S < nend; i += 2 * S) {
        float h1 = nh[i * ND + d];
        float h2 = nh[(i + S) * ND + d];
        accum_hist(h1, 1.0f, hb);
        accum_hist(h2, 1.0f, hb);
    }
    if (i < nend) accum_hist(nh[i * ND + d], 1.0f, hb);

    // edges (-1), unroll 2
    int ecnt = min((int)cur[g], CAPE);
    i = sid;
    for (; i + S < ecnt; i += 2 * S) {
        int e1 = pe[g * CAPE + i];
        int e2 = pe[g * CAPE + i + S];
        int a1 = clamp_node(ldi<I64>(ei, e1)), b1 = clamp_node(ldi<I64>(ei, NE + e1));
        int a2 = clamp_node(ldi<I64>(ei, e2)), b2 = clamp_node(ldi<I64>(ei, NE + e2));
        float w1 = ldf<BF>(ew, e1), w2 = ldf<BF>(ew, e2);
        float h1 = fmaxf(nh[a1 * ND + d], nh[b1 * ND + d]) * w1;
        float h2 = fmaxf(nh[a2 * ND + d], nh[b2 * ND + d]) * w2;
        accum_hist(h1, -1.0f, hb);
        accum_hist(h2, -1.0f, hb);
    }
    if (i < ecnt) {
        int e = pe[g * CAPE + i];
        int a = clamp_node(ldi<I64>(ei, e)), b = clamp_node(ldi<I64>(ei, NE + e));
        accum_hist(fmaxf(nh[a * ND + d], nh[b * ND + d]) * ldf<BF>(ew, e), -1.0f, hb);
    }

    // faces (+1), unroll 2
    int fcnt = min((int)cur[32 + g], CAPF);
    i = sid;
    for (; i + S < fcnt; i += 2 * S) {
        int f1 = pf[g * CAPF + i];
        int f2 = pf[g * CAPF + i + S];
        int a1 = clamp_node(ldi<I64>(fc, f1)), b1 = clamp_node(ldi<I64>(fc, NF + f1));
        int c1 = clamp_node(ldi<I64>(fc, 2*NF + f1));
        int a2 = clamp_node(ldi<I64>(fc, f2)), b2 = clamp_node(ldi<I64>(fc, NF + f2));
        int c2 = clamp_node(ldi<I64>(fc, 2*NF + f2));
        float w1 = ldf<BF>(fw, f1), w2 = ldf<BF>(fw, f2);
        float h1 = fmaxf(fmaxf(nh[a1*ND+d], nh[b1*ND+d]), nh[c1*ND+d]) * w1;
        float h2 = fmaxf(fmaxf(nh[a2*ND+d], nh[b2*ND+d]), nh[c2*ND+d]) * w2;
        accum_hist(h1, 1.0f, hb);
        accum_hist(h2, 1.0f, hb);
    }
    if (i < fcnt) {
        int f = pf[g * CAPF + i];
        int a = clamp_node(ldi<I64>(fc, f)), b = clamp_node(ldi<I64>(fc, NF + f));
        int c = clamp_node(ldi<I64>(fc, 2*NF + f));
        accum_hist(fmaxf(fmaxf(nh[a*ND+d], nh[b*ND+d]), nh[c*ND+d]) * ldf<BF>(fw, f),
                   1.0f, hb);
    }

    __syncthreads();
    // collapse 4 wave copies with full block, then prefix over j; one atomic/(j,d)
    for (int o = t; o < HBINS * 64; o += 256)
        hist[o] += hist[HBINS*64 + o] + hist[2*HBINS*64 + o] + hist[3*HBINS*64 + o];
    __syncthreads();
    if (t < 64) {
        float run = 0.0f;
        float* eb = eccf + g * (NB * ND) + t;
        for (int j = 0; j < 32; j++) {
            run += hist[j * 64 + t];
            atomicAdd(eb + j * 64, run);
        }
    }
}
__global__ __launch_bounds__(256, 4) void k_ecc(const int* __restrict__ ei,
                                                const int* __restrict__ fc,
                                                const void* __restrict__ ew,
                                                const void* __restrict__ fw,
                                                const float* __restrict__ nh,
                                                const int* __restrict__ wsi,
                                                const unsigned* __restrict__ cur,
                                                float* __restrict__ eccf,
                                                const unsigned short* __restrict__ pe,
                                                const unsigned short* __restrict__ pf,
                                                const void* __restrict__ x) {
    __shared__ float hist[4 * HBINS * 64];         // 35.8 KB, wave-private copies
    bool bf = detect_bf(x), i64 = detect_i64(ei);
    if (bf)  { if (i64) ecc_body<true,true >(ei,fc,ew,fw,nh,wsi,cur,eccf,pe,pf,hist);
               else     ecc_body<true,false>(ei,fc,ew,fw,nh,wsi,cur,eccf,pe,pf,hist); }
    else     { if (i64) ecc_body<false,true >(ei,fc,ew,fw,nh,wsi,cur,eccf,pe,pf,hist);
               else     ecc_body<false,false>(ei,fc,ew,fw,nh,wsi,cur,eccf,pe,pf,hist); }
}

// K2: MLP layer 1 + fused flat-output flush. grid = 32 graphs x 8 hid-chunks.
template<bool BF>
__device__ __forceinline__ void mlp1_body(const void* W1, const void* b1,
                                          const float* eccf, float* hbuf,
                                          void* outv, float* red, float* pr) {
    int g = blockIdx.x >> 3, hc = blockIdx.x & 7;
    int t = threadIdx.x;

    const float4* fp = (const float4*)(eccf + g * (NB * ND) + t * 8);
    float4 fa = fp[0], fb = fp[1];
    float fl[8] = {fa.x, fa.y, fa.z, fa.w, fb.x, fb.y, fb.z, fb.w};

    if (hc == 0) {                              // flush flat output (once per graph)
        int ob = NG * NCLS + g * (NB * ND) + t * 8;
        if (BF) {
#pragma unroll
            for (int j = 0; j < 8; j++)
                ((__hip_bfloat16*)outv)[ob + j] = __float2bfloat16(fl[j]);
        } else {
            ((float4*)((float*)outv + ob))[0] = fa;
            ((float4*)((float*)outv + ob))[1] = fb;
        }
    }

    float acc[32];
#pragma unroll
    for (int r = 0; r < 32; r++) acc[r] = 0.0f;
#pragma unroll 4
    for (int r = 0; r < 32; r++) {
        size_t wb = (size_t)(hc * 32 + r) * (NB * ND) + t * 8;
        float wv[8];
        if (BF) {
            uint4 u = *(const uint4*)((const __hip_bfloat16*)W1 + wb);
            wv[0] = __uint_as_float(u.x << 16); wv[1] = __uint_as_float(u.x & 0xffff0000u);
            wv[2] = __uint_as_float(u.y << 16); wv[3] = __uint_as_float(u.y & 0xffff0000u);
            wv[4] = __uint_as_float(u.z << 16); wv[5] = __uint_as_float(u.z & 0xffff0000u);
            wv[6] = __uint_as_float(u.w << 16); wv[7] = __uint_as_float(u.w & 0xffff0000u);
        } else {
            float4 a = *(const float4*)((const float*)W1 + wb);
            float4 b = *(const float4*)((const float*)W1 + wb + 4);
            wv[0]=a.x; wv[1]=a.y; wv[2]=a.z; wv[3]=a.w;
            wv[4]=b.x; wv[5]=b.y; wv[6]=b.z; wv[7]=b.w;
        }
        float s = 0.0f;
#pragma unroll
        for (int j = 0; j < 8; j++) s = fmaf(wv[j], fl[j], s);
        acc[r] = s;
    }

#pragma unroll
    for (int r = 0; r < 32; r++) red[t * 33 + r] = acc[r];
    __syncthreads();
    {
        int r = t >> 3, s8 = t & 7;
        float sum = 0.0f;
#pragma unroll
        for (int i = 0; i < 32; i++) sum += red[(s8 * 32 + i) * 33 + r];
        pr[r * 8 + s8] = sum;
    }
    __syncthreads();
    if (t < 32) {
        float h = ldf<BF>(b1, hc * 32 + t);
#pragma unroll
        for (int s8 = 0; s8 < 8; s8++) h += pr[t * 8 + s8];
        hbuf[g * HIDN + hc * 32 + t] = fmaxf(h, 0.0f);
    }
}
__global__ __launch_bounds__(256) void k_mlp1(const void* __restrict__ W1,
                                              const void* __restrict__ b1,
                                              const float* __restrict__ eccf,
                                              float* __restrict__ hbuf,
                                              void* __restrict__ outv,
                                              const void* __restrict__ x) {
    __shared__ float red[256 * 33];
    __shared__ float pr[256];
    if (detect_bf(x)) mlp1_body<true>(W1, b1, eccf, hbuf, outv, red, pr);
    else              mlp1_body<false>(W1, b1, eccf, hbuf, outv, red, pr);
}

// K3: MLP layer 2. one block per graph; wave per class, shuffle reduce.
template<bool BF>
__device__ __forceinline__ void mlp2_body(const void* W2, const void* b2,
                                          const float* hbuf, void* outv, float* hs) {
    int g = blockIdx.x, t = threadIdx.x;
    hs[t] = hbuf[g * HIDN + t];
    __syncthreads();
    int w = t >> 6, lane = t & 63;
    for (int c = w; c < NCLS; c += 4) {
        float p = hs[lane]        * ldf<BF>(W2, c * HIDN + lane)
                + hs[lane + 64]   * ldf<BF>(W2, c * HIDN + lane + 64)
                + hs[lane + 128]  * ldf<BF>(W2, c * HIDN + lane + 128)
                + hs[lane + 192]  * ldf<BF>(W2, c * HIDN + lane + 192);
#pragma unroll
        for (int off = 32; off >= 1; off >>= 1) p += __shfl_xor(p, off);
        if (lane == 0) {
            float r = p + ldf<BF>(b2, c);
            if (BF) ((__hip_bfloat16*)outv)[g * NCLS + c] = __float2bfloat16(r);
            else    ((float*)outv)[g * NCLS + c] = r;
        }
    }
}
__global__ __launch_bounds__(256) void k_mlp2(const void* __restrict__ W2,
                                              const void* __restrict__ b2,
                                              const float* __restrict__ hbuf,
                                              void* __restrict__ outv,
                                              const void* __restrict__ x) {
    __shared__ float hs[HIDN];
    if (detect_bf(x)) mlp2_body<true>(W2, b2, hbuf, outv, hs);
    else              mlp2_body<false>(W2, b2, hbuf, outv, hs);
}

extern "C" void kernel_launch(void* const* d_in, const int* in_sizes, int n_in,
                              void* d_out, int out_size, void* d_ws, size_t ws_size,
                              hipStream_t stream) {
    const void* x  = d_in[0];
    const void* nw = d_in[1];
    const void* ew = d_in[2];
    const void* fw = d_in[3];
    const void* v  = d_in[4];
    const void* W1 = d_in[5];
    const void* b1 = d_in[6];
    const void* W2 = d_in[7];
    const void* b2 = d_in[8];
    const int* ei    = (const int*)d_in[9];
    const int* fc    = (const int*)d_in[10];
    const int* batch = (const int*)d_in[11];

    float*    wsf = (float*)d_ws;
    unsigned* wsu = (unsigned*)d_ws;
    int*      wsi = (int*)d_ws;
    float*    nh   = wsf + NH_OFF;
    float*    eccf = wsf + ECCF_OFF;
    unsigned* cur  = wsu + CUR_OFF;
    float*    hbuf = wsf + HB_OFF;
    unsigned short* pe = (unsigned short*)(wsi + PE_OFF);
    unsigned short* pf = (unsigned short*)(wsi + PF_OFF);

    // zero append cursors (256 B)
    hipMemsetAsync((char*)d_ws + (size_t)CUR_OFF * 4, 0, 64 * 4, stream);

    k_pre<<<PREB, 256, 0, stream>>>(x, nw, v, ei, fc, batch, wsf, wsi, cur, pe, pf);
    k_ecc<<<NG * CHB, 256, 0, stream>>>(ei, fc, ew, fw, nh, wsi, cur, eccf, pe, pf, x);
    k_mlp1<<<NG * 8, 256, 0, stream>>>(W1, b1, eccf, hbuf, d_out, x);
    k_mlp2<<<NG, 256, 0, stream>>>(W2, b2, hbuf, d_out, x);
}

// Round 17
// 127.065 us; speedup vs baseline: 1.2267x; 1.0078x over previous
//
#include <hip/hip_runtime.h>
#include <hip/hip_bf16.h>

// ---- problem constants ----
constexpr int NN = 16000, NE = 48000, NF = 32000;
constexpr int ND = 64, NB = 32, NG = 32;
constexpr int HIDN = 256, NCLS = 10;
constexpr int CHB = 32;                       // chunk-blocks per graph in k_ecc
constexpr int EFB = (NE + NF + 255) / 256;    // 313 scatter blocks (inside k_pre)
constexpr int PREB = (NN * ND) / 256;         // 4000 blocks in k_pre
constexpr int CAPE = 4096, CAPF = 4096;       // bucket capacity (mean 1500/1000)
constexpr float KLOG = 144.26950408889634f;   // 100 * log2(e)
constexpr float DLT  = 9.307710457348151f;    // (2/31) * KLOG
constexpr float INV_DLT = 0.10743849569269015f;
// 39 rows: 4 pad rows (bins -4..-1, fold targets) + 32 real + 3 upper pad.
// Tap rows (jlo+4)+m with jlo in [-4,31], m=0..3 -> rows [0,38], provably
// DISTINCT addresses -> compiler issues the 4 ds_reads in parallel (the R16
// max()-clamp made taps aliasable -> serialized 4x ds latency).
constexpr int HBINS = 39;

// ---- ws word layout (~5 MB of the 268 MB ws) ----
constexpr int NH_OFF   = 0;                       // [NN*ND] f32 node heights
constexpr int ECCF_OFF = NH_OFF + NN * ND;        // [NG*NB*ND]=65536 f32 ecc
constexpr int CUR_OFF  = ECCF_OFF + NG * NB * ND; // [64] u32 append cursors (memset)
constexpr int NOFS_OFF = CUR_OFF + 64;            // [33] i32 node boundaries
constexpr int PE_OFF   = NOFS_OFF + 34;           // u16[NG*CAPE]
constexpr int PF_OFF   = PE_OFF + NG * CAPE / 2;  // u16[NG*CAPF]
constexpr int HB_OFF   = PF_OFF + NG * CAPF / 2;  // [NG*HIDN] f32 hidden acts
constexpr int ZERO_CNT = NG * NB * ND;            // eccf zeroed in k_pre

__device__ __forceinline__ int clamp_node(int n) {
    return ((unsigned)n < (unsigned)NN) ? n : 0;
}
template<bool BF> __device__ __forceinline__ float ldf(const void* p, int i) {
    return BF ? __bfloat162float(((const __hip_bfloat16*)p)[i]) : ((const float*)p)[i];
}
template<bool I64> __device__ __forceinline__ int ldi(const int* p, int i) {
    return I64 ? p[2 * i] : p[i];
}

// per-block dtype self-detection (wave-uniform via ballot)
__device__ __forceinline__ bool detect_bf(const void* xp) {
    const unsigned* xw = (const unsigned*)xp;
    unsigned w = xw[threadIdx.x & 63];
    return __ballot(((w >> 23) & 0xFFu) >= 200u) != 0ull;
}
__device__ __forceinline__ bool detect_i64(const int* eip) {
    const unsigned* eiw = (const unsigned*)eip;
    unsigned o = eiw[2 * (threadIdx.x & 63) + 1];
    return __ballot(o != 0u) == 0ull;
}

// 4-tap delta-histogram sigmoid with alias-free taps.
// jlo >= 32: all bins ~0, skip. jlo < -4: all bins ~1 -> one delta at bin 0
// (row 4). Else 4 taps at rows (jlo+4)+0..3 (distinct immediates off one
// base -> 4 parallel ds_reads, single latency exposure). Numerically
// identical to the R13-R16 max()-fold version (err <= 6.5e-5/element).
__device__ __forceinline__ void accum_hist(float h, float s, float* hb) {
    const float KDEC = __builtin_amdgcn_exp2f(-DLT);
    float hkL = fmaf(h, KLOG, KLOG);              // t_j = hkL - j*DLT
    float fl = floorf((hkL - 14.0f) * INV_DLT);
    int jlo = (int)fl + 1;                        // first j with t_j < 14
    if (jlo >= 32) return;                        // everything ~0
    if (jlo < -4) { hb[4 * 64] += s; return; }    // fully saturated: delta at bin 0
    float t0 = fmaf(-(fl + 1.0f), DLT, hkL);      // t at jlo, in [4.69, 14)
    float e  = __builtin_amdgcn_exp2f(t0);
    float s0 = __builtin_amdgcn_rcpf(1.0f + e);  e *= KDEC;
    float s1 = __builtin_amdgcn_rcpf(1.0f + e);  e *= KDEC;
    float s2 = __builtin_amdgcn_rcpf(1.0f + e);
    float* p = hb + (jlo + 4) * 64;
    float v0 = p[0], v1 = p[64], v2 = p[128], v3 = p[192];   // parallel ds_reads
    p[0]   = v0 + s * s0;
    p[64]  = v1 + s * (s1 - s0);
    p[128] = v2 + s * (s2 - s1);
    p[192] = v3 + s * (1.0f - s2);
}

// K0: fused prelude — heights, eccf zero, node boundaries, append-scatter.
template<bool BF, bool I64>
__device__ __forceinline__ void pre_body(const void* x, const void* nw, const void* v,
                                         const int* ei, const int* fc, const int* batch,
                                         float* wsf, int* wsi, unsigned* cur,
                                         unsigned short* pe, unsigned short* pf,
                                         unsigned* cnt, unsigned* base) {
    int t = threadIdx.x;
    int gid = blockIdx.x * 256 + t;

    if (gid < ZERO_CNT) wsf[ECCF_OFF + gid] = 0.0f;

    if (gid < NN) {                                // node range boundaries
        int gn = ldi<I64>(batch, gid) & (NG - 1);
        int gp = (gid > 0) ? (ldi<I64>(batch, gid - 1) & (NG - 1)) : -1;
        for (int gg = gp + 1; gg <= gn; gg++) wsi[NOFS_OFF + gg] = gid;
        if (gid == NN - 1)
            for (int gg = gn + 1; gg <= NG; gg++) wsi[NOFS_OFF + gg] = NN;
    }

    {                                              // heights: gid in [0, NN*ND)
        int n = gid >> 6, d = gid & 63;
        float h = fmaf(ldf<BF>(x, n*3+2), ldf<BF>(v, 2*ND+d),
                  fmaf(ldf<BF>(x, n*3+1), ldf<BF>(v, ND+d),
                       ldf<BF>(x, n*3+0) * ldf<BF>(v, d))) * ldf<BF>(nw, n);
        wsf[NH_OFF + gid] = h;
    }

    if (blockIdx.x < EFB) {                        // append-scatter (block-uniform)
        if (t < 64) cnt[t] = 0;
        __syncthreads();
        int id = blockIdx.x * 256 + t;
        int bin = 0; unsigned rank = 0; bool act = false;
        if (id < NE + NF) {
            if (id < NE) bin = ldi<I64>(batch, clamp_node(ldi<I64>(ei, id))) & 31;
            else bin = 32 + (ldi<I64>(batch, clamp_node(ldi<I64>(fc, id - NE))) & 31);
            act = true;
            rank = atomicAdd(&cnt[bin], 1u);
        }
        __syncthreads();
        if (t < 64) base[t] = cnt[t] ? atomicAdd(&cur[t], cnt[t]) : 0u;
        __syncthreads();
        if (act) {
            int off = (int)(base[bin] + rank);
            if (bin < 32) { if (off < CAPE) pe[bin * CAPE + off] = (unsigned short)id; }
            else { if (off < CAPF) pf[(bin - 32) * CAPF + off] = (unsigned short)(id - NE); }
        }
    }
}
__global__ __launch_bounds__(256) void k_pre(const void* __restrict__ x,
                                             const void* __restrict__ nw,
                                             const void* __restrict__ v,
                                             const int* __restrict__ ei,
                                             const int* __restrict__ fc,
                                             const int* __restrict__ batch,
                                             float* __restrict__ wsf,
                                             int* __restrict__ wsi,
                                             unsigned* __restrict__ cur,
                                             unsigned short* __restrict__ pe,
                                             unsigned short* __restrict__ pf) {
    __shared__ unsigned cnt[64], base[64];
    bool bf = detect_bf(x), i64 = detect_i64(ei);
    if (bf)  { if (i64) pre_body<true,true >(x,nw,v,ei,fc,batch,wsf,wsi,cur,pe,pf,cnt,base);
               else     pre_body<true,false>(x,nw,v,ei,fc,batch,wsf,wsi,cur,pe,pf,cnt,base); }
    else     { if (i64) pre_body<false,true >(x,nw,v,ei,fc,batch,wsf,wsi,cur,pe,pf,cnt,base);
               else     pre_body<false,false>(x,nw,v,ei,fc,batch,wsf,wsi,cur,pe,pf,cnt,base); }
}

// K1: ecc via wave-private LDS delta-histograms; 2-element unrolled streams.
template<bool BF, bool I64>
__device__ __forceinline__ void ecc_body(const int* ei, const int* fc,
                                         const void* ew, const void* fw,
                                         const float* nh, const int* wsi,
                                         const unsigned* cur, float* eccf,
                                         const unsigned short* pe,
                                         const unsigned short* pf,
                                         float* hist) {
    int t = threadIdx.x;
    int d = t & 63;
    int w = __builtin_amdgcn_readfirstlane(t) >> 6;
    int g  = blockIdx.x >> 5;                 // / CHB
    int cb = blockIdx.x & (CHB - 1);
    int sid = cb * 4 + w;
    const int S = CHB * 4;                    // 128 streams per graph

    for (int j = t; j < 4 * HBINS * 64; j += 256) hist[j] = 0.0f;
    __syncthreads();

    float* hb = hist + w * (HBINS * 64) + d;  // wave-private copy, lane-owned column

    // nodes (+1), unroll 2
    int ns = wsi[NOFS_OFF + g], nend = wsi[NOFS_OFF + g + 1];
    int i = ns + sid;
    for (; i + S < nend; i += 2 * S) {
        float h1 = nh[i * ND + d];
        float h2 = nh[(i + S) * ND + d];
        accum_hist(h1, 1.0f, hb);
        accum_hist(h2, 1.0f, hb);
    }
    if (i < nend) accum_hist(nh[i * ND + d], 1.0f, hb);

    // edges (-1), unroll 2
    int ecnt = min((int)cur[g], CAPE);
    i = sid;
    for (; i + S < ecnt; i += 2 * S) {
        int e1 = pe[g * CAPE + i];
        int e2 = pe[g * CAPE + i + S];
        int a1 = clamp_node(ldi<I64>(ei, e1)), b1 = clamp_node(ldi<I64>(ei, NE + e1));
        int a2 = clamp_node(ldi<I64>(ei, e2)), b2 = clamp_node(ldi<I64>(ei, NE + e2));
        float w1 = ldf<BF>(ew, e1), w2 = ldf<BF>(ew, e2);
        float h1 = fmaxf(nh[a1 * ND + d], nh[b1 * ND + d]) * w1;
        float h2 = fmaxf(nh[a2 * ND + d], nh[b2 * ND + d]) * w2;
        accum_hist(h1, -1.0f, hb);
        accum_hist(h2, -1.0f, hb);
    }
    if (i < ecnt) {
        int e = pe[g * CAPE + i];
        int a = clamp_node(ldi<I64>(ei, e)), b = clamp_node(ldi<I64>(ei, NE + e));
        accum_hist(fmaxf(nh[a * ND + d], nh[b * ND + d]) * ldf<BF>(ew, e), -1.0f, hb);
    }

    // faces (+1), unroll 2
    int fcnt = min((int)cur[32 + g], CAPF);
    i = sid;
    for (; i + S < fcnt; i += 2 * S) {
        int f1 = pf[g * CAPF + i];
        int f2 = pf[g * CAPF + i + S];
        int a1 = clamp_node(ldi<I64>(fc, f1)), b1 = clamp_node(ldi<I64>(fc, NF + f1));
        int c1 = clamp_node(ldi<I64>(fc, 2*NF + f1));
        int a2 = clamp_node(ldi<I64>(fc, f2)), b2 = clamp_node(ldi<I64>(fc, NF + f2));
        int c2 = clamp_node(ldi<I64>(fc, 2*NF + f2));
        float w1 = ldf<BF>(fw, f1), w2 = ldf<BF>(fw, f2);
        float h1 = fmaxf(fmaxf(nh[a1*ND+d], nh[b1*ND+d]), nh[c1*ND+d]) * w1;
        float h2 = fmaxf(fmaxf(nh[a2*ND+d], nh[b2*ND+d]), nh[c2*ND+d]) * w2;
        accum_hist(h1, 1.0f, hb);
        accum_hist(h2, 1.0f, hb);
    }
    if (i < fcnt) {
        int f = pf[g * CAPF + i];
        int a = clamp_node(ldi<I64>(fc, f)), b = clamp_node(ldi<I64>(fc, NF + f));
        int c = clamp_node(ldi<I64>(fc, 2*NF + f));
        accum_hist(fmaxf(fmaxf(nh[a*ND+d], nh[b*ND+d]), nh[c*ND+d]) * ldf<BF>(fw, f),
                   1.0f, hb);
    }

    __syncthreads();
    // collapse 4 wave copies, then prefix over rows; one atomic per (j,d).
    // run seeds with the 4 pad rows (bins < 0 fold) then walks real bins.
    for (int o = t; o < HBINS * 64; o += 256)
        hist[o] += hist[HBINS*64 + o] + hist[2*HBINS*64 + o] + hist[3*HBINS*64 + o];
    __syncthreads();
    if (t < 64) {
        float run = hist[t] + hist[64 + t] + hist[128 + t] + hist[192 + t];
        float* eb = eccf + g * (NB * ND) + t;
        for (int j = 0; j < 32; j++) {
            run += hist[(j + 4) * 64 + t];
            atomicAdd(eb + j * 64, run);
        }
    }
}
__global__ __launch_bounds__(256, 4) void k_ecc(const int* __restrict__ ei,
                                                const int* __restrict__ fc,
                                                const void* __restrict__ ew,
                                                const void* __restrict__ fw,
                                                const float* __restrict__ nh,
                                                const int* __restrict__ wsi,
                                                const unsigned* __restrict__ cur,
                                                float* __restrict__ eccf,
                                                const unsigned short* __restrict__ pe,
                                                const unsigned short* __restrict__ pf,
                                                const void* __restrict__ x) {
    __shared__ float hist[4 * HBINS * 64];         // 39.9 KB; 4 blocks/CU = 159.7 KB
    bool bf = detect_bf(x), i64 = detect_i64(ei);
    if (bf)  { if (i64) ecc_body<true,true >(ei,fc,ew,fw,nh,wsi,cur,eccf,pe,pf,hist);
               else     ecc_body<true,false>(ei,fc,ew,fw,nh,wsi,cur,eccf,pe,pf,hist); }
    else     { if (i64) ecc_body<false,true >(ei,fc,ew,fw,nh,wsi,cur,eccf,pe,pf,hist);
               else     ecc_body<false,false>(ei,fc,ew,fw,nh,wsi,cur,eccf,pe,pf,hist); }
}

// K2: MLP layer 1 + fused flat-output flush. grid = 32 graphs x 8 hid-chunks.
template<bool BF>
__device__ __forceinline__ void mlp1_body(const void* W1, const void* b1,
                                          const float* eccf, float* hbuf,
                                          void* outv, float* red, float* pr) {
    int g = blockIdx.x >> 3, hc = blockIdx.x & 7;
    int t = threadIdx.x;

    const float4* fp = (const float4*)(eccf + g * (NB * ND) + t * 8);
    float4 fa = fp[0], fb = fp[1];
    float fl[8] = {fa.x, fa.y, fa.z, fa.w, fb.x, fb.y, fb.z, fb.w};

    if (hc == 0) {                              // flush flat output (once per graph)
        int ob = NG * NCLS + g * (NB * ND) + t * 8;
        if (BF) {
#pragma unroll
            for (int j = 0; j < 8; j++)
                ((__hip_bfloat16*)outv)[ob + j] = __float2bfloat16(fl[j]);
        } else {
            ((float4*)((float*)outv + ob))[0] = fa;
            ((float4*)((float*)outv + ob))[1] = fb;
        }
    }

    float acc[32];
#pragma unroll
    for (int r = 0; r < 32; r++) acc[r] = 0.0f;
#pragma unroll 4
    for (int r = 0; r < 32; r++) {
        size_t wb = (size_t)(hc * 32 + r) * (NB * ND) + t * 8;
        float wv[8];
        if (BF) {
            uint4 u = *(const uint4*)((const __hip_bfloat16*)W1 + wb);
            wv[0] = __uint_as_float(u.x << 16); wv[1] = __uint_as_float(u.x & 0xffff0000u);
            wv[2] = __uint_as_float(u.y << 16); wv[3] = __uint_as_float(u.y & 0xffff0000u);
            wv[4] = __uint_as_float(u.z << 16); wv[5] = __uint_as_float(u.z & 0xffff0000u);
            wv[6] = __uint_as_float(u.w << 16); wv[7] = __uint_as_float(u.w & 0xffff0000u);
        } else {
            float4 a = *(const float4*)((const float*)W1 + wb);
            float4 b = *(const float4*)((const float*)W1 + wb + 4);
            wv[0]=a.x; wv[1]=a.y; wv[2]=a.z; wv[3]=a.w;
            wv[4]=b.x; wv[5]=b.y; wv[6]=b.z; wv[7]=b.w;
        }
        float s = 0.0f;
#pragma unroll
        for (int j = 0; j < 8; j++) s = fmaf(wv[j], fl[j], s);
        acc[r] = s;
    }

#pragma unroll
    for (int r = 0; r < 32; r++) red[t * 33 + r] = acc[r];
    __syncthreads();
    {
        int r = t >> 3, s8 = t & 7;
        float sum = 0.0f;
#pragma unroll
        for (int i = 0; i < 32; i++) sum += red[(s8 * 32 + i) * 33 + r];
        pr[r * 8 + s8] = sum;
    }
    __syncthreads();
    if (t < 32) {
        float h = ldf<BF>(b1, hc * 32 + t);
#pragma unroll
        for (int s8 = 0; s8 < 8; s8++) h += pr[t * 8 + s8];
        hbuf[g * HIDN + hc * 32 + t] = fmaxf(h, 0.0f);
    }
}
__global__ __launch_bounds__(256) void k_mlp1(const void* __restrict__ W1,
                                              const void* __restrict__ b1,
                                              const float* __restrict__ eccf,
                                              float* __restrict__ hbuf,
                                              void* __restrict__ outv,
                                              const void* __restrict__ x) {
    __shared__ float red[256 * 33];
    __shared__ float pr[256];
    if (detect_bf(x)) mlp1_body<true>(W1, b1, eccf, hbuf, outv, red, pr);
    else              mlp1_body<false>(W1, b1, eccf, hbuf, outv, red, pr);
}

// K3: MLP layer 2. one block per graph; wave per class, shuffle reduce.
template<bool BF>
__device__ __forceinline__ void mlp2_body(const void* W2, const void* b2,
                                          const float* hbuf, void* outv, float* hs) {
    int g = blockIdx.x, t = threadIdx.x;
    hs[t] = hbuf[g * HIDN + t];
    __syncthreads();
    int w = t >> 6, lane = t & 63;
    for (int c = w; c < NCLS; c += 4) {
        float p = hs[lane]        * ldf<BF>(W2, c * HIDN + lane)
                + hs[lane + 64]   * ldf<BF>(W2, c * HIDN + lane + 64)
                + hs[lane + 128]  * ldf<BF>(W2, c * HIDN + lane + 128)
                + hs[lane + 192]  * ldf<BF>(W2, c * HIDN + lane + 192);
#pragma unroll
        for (int off = 32; off >= 1; off >>= 1) p += __shfl_xor(p, off);
        if (lane == 0) {
            float r = p + ldf<BF>(b2, c);
            if (BF) ((__hip_bfloat16*)outv)[g * NCLS + c] = __float2bfloat16(r);
            else    ((float*)outv)[g * NCLS + c] = r;
        }
    }
}
__global__ __launch_bounds__(256) void k_mlp2(const void* __restrict__ W2,
                                              const void* __restrict__ b2,
                                              const float* __restrict__ hbuf,
                                              void* __restrict__ outv,
                                              const void* __restrict__ x) {
    __shared__ float hs[HIDN];
    if (detect_bf(x)) mlp2_body<true>(W2, b2, hbuf, outv, hs);
    else              mlp2_body<false>(W2, b2, hbuf, outv, hs);
}

extern "C" void kernel_launch(void* const* d_in, const int* in_sizes, int n_in,
                              void* d_out, int out_size, void* d_ws, size_t ws_size,
                              hipStream_t stream) {
    const void* x  = d_in[0];
    const void* nw = d_in[1];
    const void* ew = d_in[2];
    const void* fw = d_in[3];
    const void* v  = d_in[4];
    const void* W1 = d_in[5];
    const void* b1 = d_in[6];
    const void* W2 = d_in[7];
    const void* b2 = d_in[8];
    const int* ei    = (const int*)d_in[9];
    const int* fc    = (const int*)d_in[10];
    const int* batch = (const int*)d_in[11];

    float*    wsf = (float*)d_ws;
    unsigned* wsu = (unsigned*)d_ws;
    int*      wsi = (int*)d_ws;
    float*    nh   = wsf + NH_OFF;
    float*    eccf = wsf + ECCF_OFF;
    unsigned* cur  = wsu + CUR_OFF;
    float*    hbuf = wsf + HB_OFF;
    unsigned short* pe = (unsigned short*)(wsi + PE_OFF);
    unsigned short* pf = (unsigned short*)(wsi + PF_OFF);

    // zero append cursors (256 B)
    hipMemsetAsync((char*)d_ws + (size_t)CUR_OFF * 4, 0, 64 * 4, stream);

    k_pre<<<PREB, 256, 0, stream>>>(x, nw, v, ei, fc, batch, wsf, wsi, cur, pe, pf);
    k_ecc<<<NG * CHB, 256, 0, stream>>>(ei, fc, ew, fw, nh, wsi, cur, eccf, pe, pf, x);
    k_mlp1<<<NG * 8, 256, 0, stream>>>(W1, b1, eccf, hbuf, d_out, x);
    k_mlp2<<<NG, 256, 0, stream>>>(W2, b2, hbuf, d_out, x);
}

// Round 18
// 124.383 us; speedup vs baseline: 1.2531x; 1.0216x over previous
//
#include <hip/hip_runtime.h>
#include <hip/hip_bf16.h>

// ---- problem constants ----
constexpr int NN = 16000, NE = 48000, NF = 32000;
constexpr int ND = 64, NB = 32, NG = 32;
constexpr int HIDN = 256, NCLS = 10;
constexpr int CHB = 32;                       // chunk-blocks per graph in k_ecc
constexpr int EFB = (NE + NF + 255) / 256;    // 313 scatter blocks (inside k_pre)
constexpr int PREB = (NN * ND) / 256;         // 4000 blocks in k_pre
constexpr int CAPE = 4096, CAPF = 4096;       // bucket capacity (mean 1500/1000)
constexpr float KLOG = 144.26950408889634f;   // 100 * log2(e)
constexpr float DLT  = 9.307710457348151f;    // (2/31) * KLOG
constexpr float INV_DLT = 0.10743849569269015f;
constexpr int HBINS = 39;                     // 4 pad + 32 real + 3 pad (alias-free taps)

// ---- ws word layout (~5 MB of the 268 MB ws) ----
constexpr int NH_OFF   = 0;                       // [NN*ND] f32 node heights
constexpr int ECCF_OFF = NH_OFF + NN * ND;        // [NG*NB*ND]=65536 f32 ecc
constexpr int CUR_OFF  = ECCF_OFF + NG * NB * ND; // [64] u32 append cursors (memset)
constexpr int NOFS_OFF = CUR_OFF + 64;            // [33] i32 node boundaries
constexpr int PE_OFF   = NOFS_OFF + 34;           // u16[NG*CAPE]
constexpr int PF_OFF   = PE_OFF + NG * CAPE / 2;  // u16[NG*CAPF]
constexpr int HB_OFF   = PF_OFF + NG * CAPF / 2;  // [NG*HIDN] f32 hidden acts
constexpr int ZERO_CNT = NG * NB * ND;            // eccf zeroed in k_pre

__device__ __forceinline__ int clamp_node(int n) {
    return ((unsigned)n < (unsigned)NN) ? n : 0;
}
template<bool BF> __device__ __forceinline__ float ldf(const void* p, int i) {
    return BF ? __bfloat162float(((const __hip_bfloat16*)p)[i]) : ((const float*)p)[i];
}
template<bool I64> __device__ __forceinline__ int ldi(const int* p, int i) {
    return I64 ? p[2 * i] : p[i];
}

// per-block dtype self-detection (wave-uniform via ballot)
__device__ __forceinline__ bool detect_bf(const void* xp) {
    const unsigned* xw = (const unsigned*)xp;
    unsigned w = xw[threadIdx.x & 63];
    return __ballot(((w >> 23) & 0xFFu) >= 200u) != 0ull;
}
__device__ __forceinline__ bool detect_i64(const int* eip) {
    const unsigned* eiw = (const unsigned*)eip;
    unsigned o = eiw[2 * (threadIdx.x & 63) + 1];
    return __ballot(o != 0u) == 0ull;
}

// 4-tap delta-histogram sigmoid, alias-free taps (rows (jlo+4)+0..3 distinct).
__device__ __forceinline__ void accum_hist(float h, float s, float* hb) {
    const float KDEC = __builtin_amdgcn_exp2f(-DLT);
    float hkL = fmaf(h, KLOG, KLOG);              // t_j = hkL - j*DLT
    float fl = floorf((hkL - 14.0f) * INV_DLT);
    int jlo = (int)fl + 1;                        // first j with t_j < 14
    if (jlo >= 32) return;                        // everything ~0
    if (jlo < -4) { hb[4 * 64] += s; return; }    // fully saturated: delta at bin 0
    float t0 = fmaf(-(fl + 1.0f), DLT, hkL);      // t at jlo, in [4.69, 14)
    float e  = __builtin_amdgcn_exp2f(t0);
    float s0 = __builtin_amdgcn_rcpf(1.0f + e);  e *= KDEC;
    float s1 = __builtin_amdgcn_rcpf(1.0f + e);  e *= KDEC;
    float s2 = __builtin_amdgcn_rcpf(1.0f + e);
    float* p = hb + (jlo + 4) * 64;
    float v0 = p[0], v1 = p[64], v2 = p[128], v3 = p[192];   // parallel ds_reads
    p[0]   = v0 + s * s0;
    p[64]  = v1 + s * (s1 - s0);
    p[128] = v2 + s * (s2 - s1);
    p[192] = v3 + s * (1.0f - s2);
}

// K0: fused prelude — heights, eccf zero, node boundaries, append-scatter.
template<bool BF, bool I64>
__device__ __forceinline__ void pre_body(const void* x, const void* nw, const void* v,
                                         const int* ei, const int* fc, const int* batch,
                                         float* wsf, int* wsi, unsigned* cur,
                                         unsigned short* pe, unsigned short* pf,
                                         unsigned* cnt, unsigned* base) {
    int t = threadIdx.x;
    int gid = blockIdx.x * 256 + t;

    if (gid < ZERO_CNT) wsf[ECCF_OFF + gid] = 0.0f;

    if (gid < NN) {                                // node range boundaries
        int gn = ldi<I64>(batch, gid) & (NG - 1);
        int gp = (gid > 0) ? (ldi<I64>(batch, gid - 1) & (NG - 1)) : -1;
        for (int gg = gp + 1; gg <= gn; gg++) wsi[NOFS_OFF + gg] = gid;
        if (gid == NN - 1)
            for (int gg = gn + 1; gg <= NG; gg++) wsi[NOFS_OFF + gg] = NN;
    }

    {                                              // heights: gid in [0, NN*ND)
        int n = gid >> 6, d = gid & 63;
        float h = fmaf(ldf<BF>(x, n*3+2), ldf<BF>(v, 2*ND+d),
                  fmaf(ldf<BF>(x, n*3+1), ldf<BF>(v, ND+d),
                       ldf<BF>(x, n*3+0) * ldf<BF>(v, d))) * ldf<BF>(nw, n);
        wsf[NH_OFF + gid] = h;
    }

    if (blockIdx.x < EFB) {                        // append-scatter (block-uniform)
        if (t < 64) cnt[t] = 0;
        __syncthreads();
        int id = blockIdx.x * 256 + t;
        int bin = 0; unsigned rank = 0; bool act = false;
        if (id < NE + NF) {
            if (id < NE) bin = ldi<I64>(batch, clamp_node(ldi<I64>(ei, id))) & 31;
            else bin = 32 + (ldi<I64>(batch, clamp_node(ldi<I64>(fc, id - NE))) & 31);
            act = true;
            rank = atomicAdd(&cnt[bin], 1u);
        }
        __syncthreads();
        if (t < 64) base[t] = cnt[t] ? atomicAdd(&cur[t], cnt[t]) : 0u;
        __syncthreads();
        if (act) {
            int off = (int)(base[bin] + rank);
            if (bin < 32) { if (off < CAPE) pe[bin * CAPE + off] = (unsigned short)id; }
            else { if (off < CAPF) pf[(bin - 32) * CAPF + off] = (unsigned short)(id - NE); }
        }
    }
}
__global__ __launch_bounds__(256) void k_pre(const void* __restrict__ x,
                                             const void* __restrict__ nw,
                                             const void* __restrict__ v,
                                             const int* __restrict__ ei,
                                             const int* __restrict__ fc,
                                             const int* __restrict__ batch,
                                             float* __restrict__ wsf,
                                             int* __restrict__ wsi,
                                             unsigned* __restrict__ cur,
                                             unsigned short* __restrict__ pe,
                                             unsigned short* __restrict__ pf) {
    __shared__ unsigned cnt[64], base[64];
    bool bf = detect_bf(x), i64 = detect_i64(ei);
    if (bf)  { if (i64) pre_body<true,true >(x,nw,v,ei,fc,batch,wsf,wsi,cur,pe,pf,cnt,base);
               else     pre_body<true,false>(x,nw,v,ei,fc,batch,wsf,wsi,cur,pe,pf,cnt,base); }
    else     { if (i64) pre_body<false,true >(x,nw,v,ei,fc,batch,wsf,wsi,cur,pe,pf,cnt,base);
               else     pre_body<false,false>(x,nw,v,ei,fc,batch,wsf,wsi,cur,pe,pf,cnt,base); }
}

// K1: ecc via wave-private LDS delta-histograms; 4-element unrolled streams
// (all four elements' gather chains issue before any sigmoid/DS work —
// deepens the latency-overlap window that unroll-2 validated in R16).
template<bool BF, bool I64>
__device__ __forceinline__ void ecc_body(const int* ei, const int* fc,
                                         const void* ew, const void* fw,
                                         const float* nh, const int* wsi,
                                         const unsigned* cur, float* eccf,
                                         const unsigned short* pe,
                                         const unsigned short* pf,
                                         float* hist) {
    int t = threadIdx.x;
    int d = t & 63;
    int w = __builtin_amdgcn_readfirstlane(t) >> 6;
    int g  = blockIdx.x >> 5;                 // / CHB
    int cb = blockIdx.x & (CHB - 1);
    int sid = cb * 4 + w;
    const int S = CHB * 4;                    // 128 streams per graph

    for (int j = t; j < 4 * HBINS * 64; j += 256) hist[j] = 0.0f;
    __syncthreads();

    float* hb = hist + w * (HBINS * 64) + d;  // wave-private copy, lane-owned column

    // nodes (+1), unroll 4
    int ns = wsi[NOFS_OFF + g], nend = wsi[NOFS_OFF + g + 1];
    int i = ns + sid;
    for (; i + 3 * S < nend; i += 4 * S) {
        float h1 = nh[i * ND + d];
        float h2 = nh[(i + S) * ND + d];
        float h3 = nh[(i + 2 * S) * ND + d];
        float h4 = nh[(i + 3 * S) * ND + d];
        accum_hist(h1, 1.0f, hb);
        accum_hist(h2, 1.0f, hb);
        accum_hist(h3, 1.0f, hb);
        accum_hist(h4, 1.0f, hb);
    }
    for (; i < nend; i += S) accum_hist(nh[i * ND + d], 1.0f, hb);

    // edges (-1), unroll 4
    int ecnt = min((int)cur[g], CAPE);
    i = sid;
    for (; i + 3 * S < ecnt; i += 4 * S) {
        int e1 = pe[g * CAPE + i];
        int e2 = pe[g * CAPE + i + S];
        int e3 = pe[g * CAPE + i + 2 * S];
        int e4 = pe[g * CAPE + i + 3 * S];
        int a1 = clamp_node(ldi<I64>(ei, e1)), b1 = clamp_node(ldi<I64>(ei, NE + e1));
        int a2 = clamp_node(ldi<I64>(ei, e2)), b2 = clamp_node(ldi<I64>(ei, NE + e2));
        int a3 = clamp_node(ldi<I64>(ei, e3)), b3 = clamp_node(ldi<I64>(ei, NE + e3));
        int a4 = clamp_node(ldi<I64>(ei, e4)), b4 = clamp_node(ldi<I64>(ei, NE + e4));
        float w1 = ldf<BF>(ew, e1), w2 = ldf<BF>(ew, e2);
        float w3 = ldf<BF>(ew, e3), w4 = ldf<BF>(ew, e4);
        float h1 = fmaxf(nh[a1 * ND + d], nh[b1 * ND + d]) * w1;
        float h2 = fmaxf(nh[a2 * ND + d], nh[b2 * ND + d]) * w2;
        float h3 = fmaxf(nh[a3 * ND + d], nh[b3 * ND + d]) * w3;
        float h4 = fmaxf(nh[a4 * ND + d], nh[b4 * ND + d]) * w4;
        accum_hist(h1, -1.0f, hb);
        accum_hist(h2, -1.0f, hb);
        accum_hist(h3, -1.0f, hb);
        accum_hist(h4, -1.0f, hb);
    }
    for (; i < ecnt; i += S) {
        int e = pe[g * CAPE + i];
        int a = clamp_node(ldi<I64>(ei, e)), b = clamp_node(ldi<I64>(ei, NE + e));
        accum_hist(fmaxf(nh[a * ND + d], nh[b * ND + d]) * ldf<BF>(ew, e), -1.0f, hb);
    }

    // faces (+1), unroll 4
    int fcnt = min((int)cur[32 + g], CAPF);
    i = sid;
    for (; i + 3 * S < fcnt; i += 4 * S) {
        int f1 = pf[g * CAPF + i];
        int f2 = pf[g * CAPF + i + S];
        int f3 = pf[g * CAPF + i + 2 * S];
        int f4 = pf[g * CAPF + i + 3 * S];
        int a1 = clamp_node(ldi<I64>(fc, f1)), b1 = clamp_node(ldi<I64>(fc, NF + f1));
        int c1 = clamp_node(ldi<I64>(fc, 2*NF + f1));
        int a2 = clamp_node(ldi<I64>(fc, f2)), b2 = clamp_node(ldi<I64>(fc, NF + f2));
        int c2 = clamp_node(ldi<I64>(fc, 2*NF + f2));
        int a3 = clamp_node(ldi<I64>(fc, f3)), b3 = clamp_node(ldi<I64>(fc, NF + f3));
        int c3 = clamp_node(ldi<I64>(fc, 2*NF + f3));
        int a4 = clamp_node(ldi<I64>(fc, f4)), b4 = clamp_node(ldi<I64>(fc, NF + f4));
        int c4 = clamp_node(ldi<I64>(fc, 2*NF + f4));
        float w1 = ldf<BF>(fw, f1), w2 = ldf<BF>(fw, f2);
        float w3 = ldf<BF>(fw, f3), w4 = ldf<BF>(fw, f4);
        float h1 = fmaxf(fmaxf(nh[a1*ND+d], nh[b1*ND+d]), nh[c1*ND+d]) * w1;
        float h2 = fmaxf(fmaxf(nh[a2*ND+d], nh[b2*ND+d]), nh[c2*ND+d]) * w2;
        float h3 = fmaxf(fmaxf(nh[a3*ND+d], nh[b3*ND+d]), nh[c3*ND+d]) * w3;
        float h4 = fmaxf(fmaxf(nh[a4*ND+d], nh[b4*ND+d]), nh[c4*ND+d]) * w4;
        accum_hist(h1, 1.0f, hb);
        accum_hist(h2, 1.0f, hb);
        accum_hist(h3, 1.0f, hb);
        accum_hist(h4, 1.0f, hb);
    }
    for (; i < fcnt; i += S) {
        int f = pf[g * CAPF + i];
        int a = clamp_node(ldi<I64>(fc, f)), b = clamp_node(ldi<I64>(fc, NF + f));
        int c = clamp_node(ldi<I64>(fc, 2*NF + f));
        accum_hist(fmaxf(fmaxf(nh[a*ND+d], nh[b*ND+d]), nh[c*ND+d]) * ldf<BF>(fw, f),
                   1.0f, hb);
    }

    __syncthreads();
    // collapse 4 wave copies, then prefix over rows; one atomic per (j,d).
    for (int o = t; o < HBINS * 64; o += 256)
        hist[o] += hist[HBINS*64 + o] + hist[2*HBINS*64 + o] + hist[3*HBINS*64 + o];
    __syncthreads();
    if (t < 64) {
        float run = hist[t] + hist[64 + t] + hist[128 + t] + hist[192 + t];
        float* eb = eccf + g * (NB * ND) + t;
        for (int j = 0; j < 32; j++) {
            run += hist[(j + 4) * 64 + t];
            atomicAdd(eb + j * 64, run);
        }
    }
}
__global__ __launch_bounds__(256, 4) void k_ecc(const int* __restrict__ ei,
                                                const int* __restrict__ fc,
                                                const void* __restrict__ ew,
                                                const void* __restrict__ fw,
                                                const float* __restrict__ nh,
                                                const int* __restrict__ wsi,
                                                const unsigned* __restrict__ cur,
                                                float* __restrict__ eccf,
                                                const unsigned short* __restrict__ pe,
                                                const unsigned short* __restrict__ pf,
                                                const void* __restrict__ x) {
    __shared__ float hist[4 * HBINS * 64];         // 39.9 KB; 4 blocks/CU = 159.7 KB
    bool bf = detect_bf(x), i64 = detect_i64(ei);
    if (bf)  { if (i64) ecc_body<true,true >(ei,fc,ew,fw,nh,wsi,cur,eccf,pe,pf,hist);
               else     ecc_body<true,false>(ei,fc,ew,fw,nh,wsi,cur,eccf,pe,pf,hist); }
    else     { if (i64) ecc_body<false,true >(ei,fc,ew,fw,nh,wsi,cur,eccf,pe,pf,hist);
               else     ecc_body<false,false>(ei,fc,ew,fw,nh,wsi,cur,eccf,pe,pf,hist); }
}

// K2: MLP layer 1 + fused flat-output flush. grid = 32 graphs x 8 hid-chunks.
template<bool BF>
__device__ __forceinline__ void mlp1_body(const void* W1, const void* b1,
                                          const float* eccf, float* hbuf,
                                          void* outv, float* red, float* pr) {
    int g = blockIdx.x >> 3, hc = blockIdx.x & 7;
    int t = threadIdx.x;

    const float4* fp = (const float4*)(eccf + g * (NB * ND) + t * 8);
    float4 fa = fp[0], fb = fp[1];
    float fl[8] = {fa.x, fa.y, fa.z, fa.w, fb.x, fb.y, fb.z, fb.w};

    if (hc == 0) {                              // flush flat output (once per graph)
        int ob = NG * NCLS + g * (NB * ND) + t * 8;
        if (BF) {
#pragma unroll
            for (int j = 0; j < 8; j++)
                ((__hip_bfloat16*)outv)[ob + j] = __float2bfloat16(fl[j]);
        } else {
            ((float4*)((float*)outv + ob))[0] = fa;
            ((float4*)((float*)outv + ob))[1] = fb;
        }
    }

    float acc[32];
#pragma unroll
    for (int r = 0; r < 32; r++) acc[r] = 0.0f;
#pragma unroll 4
    for (int r = 0; r < 32; r++) {
        size_t wb = (size_t)(hc * 32 + r) * (NB * ND) + t * 8;
        float wv[8];
        if (BF) {
            uint4 u = *(const uint4*)((const __hip_bfloat16*)W1 + wb);
            wv[0] = __uint_as_float(u.x << 16); wv[1] = __uint_as_float(u.x & 0xffff0000u);
            wv[2] = __uint_as_float(u.y << 16); wv[3] = __uint_as_float(u.y & 0xffff0000u);
            wv[4] = __uint_as_float(u.z << 16); wv[5] = __uint_as_float(u.z & 0xffff0000u);
            wv[6] = __uint_as_float(u.w << 16); wv[7] = __uint_as_float(u.w & 0xffff0000u);
        } else {
            float4 a = *(const float4*)((const float*)W1 + wb);
            float4 b = *(const float4*)((const float*)W1 + wb + 4);
            wv[0]=a.x; wv[1]=a.y; wv[2]=a.z; wv[3]=a.w;
            wv[4]=b.x; wv[5]=b.y; wv[6]=b.z; wv[7]=b.w;
        }
        float s = 0.0f;
#pragma unroll
        for (int j = 0; j < 8; j++) s = fmaf(wv[j], fl[j], s);
        acc[r] = s;
    }

#pragma unroll
    for (int r = 0; r < 32; r++) red[t * 33 + r] = acc[r];
    __syncthreads();
    {
        int r = t >> 3, s8 = t & 7;
        float sum = 0.0f;
#pragma unroll
        for (int i = 0; i < 32; i++) sum += red[(s8 * 32 + i) * 33 + r];
        pr[r * 8 + s8] = sum;
    }
    __syncthreads();
    if (t < 32) {
        float h = ldf<BF>(b1, hc * 32 + t);
#pragma unroll
        for (int s8 = 0; s8 < 8; s8++) h += pr[t * 8 + s8];
        hbuf[g * HIDN + hc * 32 + t] = fmaxf(h, 0.0f);
    }
}
__global__ __launch_bounds__(256) void k_mlp1(const void* __restrict__ W1,
                                              const void* __restrict__ b1,
                                              const float* __restrict__ eccf,
                                              float* __restrict__ hbuf,
                                              void* __restrict__ outv,
                                              const void* __restrict__ x) {
    __shared__ float red[256 * 33];
    __shared__ float pr[256];
    if (detect_bf(x)) mlp1_body<true>(W1, b1, eccf, hbuf, outv, red, pr);
    else              mlp1_body<false>(W1, b1, eccf, hbuf, outv, red, pr);
}

// K3: MLP layer 2. one block per graph; wave per class, shuffle reduce.
template<bool BF>
__device__ __forceinline__ void mlp2_body(const void* W2, const void* b2,
                                          const float* hbuf, void* outv, float* hs) {
    int g = blockIdx.x, t = threadIdx.x;
    hs[t] = hbuf[g * HIDN + t];
    __syncthreads();
    int w = t >> 6, lane = t & 63;
    for (int c = w; c < NCLS; c += 4) {
        float p = hs[lane]        * ldf<BF>(W2, c * HIDN + lane)
                + hs[lane + 64]   * ldf<BF>(W2, c * HIDN + lane + 64)
                + hs[lane + 128]  * ldf<BF>(W2, c * HIDN + lane + 128)
                + hs[lane + 192]  * ldf<BF>(W2, c * HIDN + lane + 192);
#pragma unroll
        for (int off = 32; off >= 1; off >>= 1) p += __shfl_xor(p, off);
        if (lane == 0) {
            float r = p + ldf<BF>(b2, c);
            if (BF) ((__hip_bfloat16*)outv)[g * NCLS + c] = __float2bfloat16(r);
            else    ((float*)outv)[g * NCLS + c] = r;
        }
    }
}
__global__ __launch_bounds__(256) void k_mlp2(const void* __restrict__ W2,
                                              const void* __restrict__ b2,
                                              const float* __restrict__ hbuf,
                                              void* __restrict__ outv,
                                              const void* __restrict__ x) {
    __shared__ float hs[HIDN];
    if (detect_bf(x)) mlp2_body<true>(W2, b2, hbuf, outv, hs);
    else              mlp2_body<false>(W2, b2, hbuf, outv, hs);
}

extern "C" void kernel_launch(void* const* d_in, const int* in_sizes, int n_in,
                              void* d_out, int out_size, void* d_ws, size_t ws_size,
                              hipStream_t stream) {
    const void* x  = d_in[0];
    const void* nw = d_in[1];
    const void* ew = d_in[2];
    const void* fw = d_in[3];
    const void* v  = d_in[4];
    const void* W1 = d_in[5];
    const void* b1 = d_in[6];
    const void* W2 = d_in[7];
    const void* b2 = d_in[8];
    const int* ei    = (const int*)d_in[9];
    const int* fc    = (const int*)d_in[10];
    const int* batch = (const int*)d_in[11];

    float*    wsf = (float*)d_ws;
    unsigned* wsu = (unsigned*)d_ws;
    int*      wsi = (int*)d_ws;
    float*    nh   = wsf + NH_OFF;
    float*    eccf = wsf + ECCF_OFF;
    unsigned* cur  = wsu + CUR_OFF;
    float*    hbuf = wsf + HB_OFF;
    unsigned short* pe = (unsigned short*)(wsi + PE_OFF);
    unsigned short* pf = (unsigned short*)(wsi + PF_OFF);

    // zero append cursors (256 B)
    hipMemsetAsync((char*)d_ws + (size_t)CUR_OFF * 4, 0, 64 * 4, stream);

    k_pre<<<PREB, 256, 0, stream>>>(x, nw, v, ei, fc, batch, wsf, wsi, cur, pe, pf);
    k_ecc<<<NG * CHB, 256, 0, stream>>>(ei, fc, ew, fw, nh, wsi, cur, eccf, pe, pf, x);
    k_mlp1<<<NG * 8, 256, 0, stream>>>(W1, b1, eccf, hbuf, d_out, x);
    k_mlp2<<<NG, 256, 0, stream>>>(W2, b2, hbuf, d_out, x);
}